// Round 1
// baseline (3252.510 us; speedup 1.0000x reference)
//
#include <hip/hip_runtime.h>
#include <cstdint>

#define T_LEN 2048
#define NB    32
#define NROWS (NB*T_LEN)   // 65536
#define HH    200
#define G4    800
#define TB    256          // LSTM time-chunk (per dispatch)
#define SB    16           // step block staged in LDS

typedef _Float16 f16;
typedef _Float16 f16x2 __attribute__((ext_vector_type(2)));
typedef _Float16 f16x8 __attribute__((ext_vector_type(8)));
typedef float   floatx4 __attribute__((ext_vector_type(4)));

#define GLD_LDS16(g, l) __builtin_amdgcn_global_load_lds( \
    (const __attribute__((address_space(1))) void*)(g), \
    (__attribute__((address_space(3))) void*)(l), 16, 0, 0)

static __device__ __forceinline__ unsigned short f2h(float x) {
  f16 h = (f16)x; return __builtin_bit_cast(unsigned short, h);
}
static __device__ __forceinline__ float h2f(unsigned short u) {
  return (float)__builtin_bit_cast(f16, u);
}
static __device__ __forceinline__ float dot2f(unsigned int a, unsigned int b, float c) {
  return __builtin_amdgcn_fdot2(__builtin_bit_cast(f16x2, a),
                                __builtin_bit_cast(f16x2, b), c, false);
}
static __device__ __forceinline__ float sigm(float x) {
  return __builtin_amdgcn_rcpf(1.f + __expf(-x));
}
static __device__ __forceinline__ float tanh_fast(float x) {
  return 1.f - 2.f * __builtin_amdgcn_rcpf(__expf(2.f * x) + 1.f);
}
// butterfly sum over a lane-quad (lanes 4k..4k+3): after this all 4 lanes hold the sum
static __device__ __forceinline__ float qsum4(float x) {
  int v1 = __builtin_amdgcn_update_dpp(0, __builtin_bit_cast(int, x), 0xB1, 0xF, 0xF, true); // quad_perm [1,0,3,2]
  x += __builtin_bit_cast(float, v1);
  int v2 = __builtin_amdgcn_update_dpp(0, __builtin_bit_cast(int, x), 0x4E, 0xF, 0xF, true); // quad_perm [2,3,0,1]
  x += __builtin_bit_cast(float, v2);
  return x;
}

// ---------------- P/Q precompute: P[dt,co]=sum_ci relu(k1)k2, Q with relu(-k1)
__global__ void pq_kernel(const float* __restrict__ k1w, const float* __restrict__ k2w,
                          float* __restrict__ PQ) {
  int id = blockIdx.x * 256 + threadIdx.x;   // 1536 total
  int pq = id / 768;
  int rem = id % 768;
  int wdt = rem / 256;
  int co  = rem % 256;
  float acc = 0.f;
  for (int ci = 0; ci < 256; ++ci) {
    float k = k1w[ci];
    float kk = pq ? fmaxf(-k, 0.f) : fmaxf(k, 0.f);
    acc += kk * k2w[((size_t)wdt * 256 + ci) * 256 + co];
  }
  PQ[id] = acc;
}

// ---------------- f16 weight prep (B matrices stored TRANSPOSED: [n][k])
// K3T[co][ci] ; Wx2[dir][c][k] with permuted col c=4n+q (gate g=q*200+n) ;
// Whp[dir][s][u][q'][64]: k-split chunks for the lstm (q' = 2*q + m, unit n=2u+m,
//   halves kk<50 hold W[256+s*50+kk][g], rest pad) ; bcat permuted, f-gate +1 folded.
__global__ void prep_kernel(const float* __restrict__ k3w,
                            const float* __restrict__ Wf, const float* __restrict__ bfv,
                            const float* __restrict__ Wb, const float* __restrict__ bbv,
                            unsigned short* __restrict__ K3h, unsigned short* __restrict__ Wx2,
                            unsigned short* __restrict__ Whp, float* __restrict__ bcat) {
  int id = blockIdx.x * 256 + threadIdx.x;
  if (id < 65536) {                      // K3T[co*256+ci] = k3w[ci*256+co]
    K3h[id] = f2h(k3w[(id & 255) * 256 + (id >> 8)]);
    return;
  }
  id -= 65536;
  if (id < 409600) {                     // Wx2[dir][c<800][k<256]
    int dirv = id / 204800;
    int r = id % 204800;
    int c = r >> 8, k = r & 255;
    int n = c >> 2, q = c & 3;
    int g = q * 200 + n;
    const float* W = dirv ? Wb : Wf;
    Wx2[id] = f2h(W[k * 800 + g]);
    return;
  }
  id -= 409600;
  if (id < 409600) {                     // Whp[((dir*4+s)*100+u)*8 + q'][64]
    int kk = id & 63;
    int r  = id >> 6;        // 0..6399
    int qp = r & 7;
    int t2 = r >> 3;         // 0..799
    int u  = t2 % 100;
    int sr = t2 / 100;       // 0..7
    int s  = sr & 3, dirv = sr >> 2;
    int q  = qp >> 1, m = qp & 1;
    int n  = 2 * u + m;
    int g  = q * 200 + n;
    int k  = s * 50 + kk;
    const float* W = dirv ? Wb : Wf;
    float v = (kk < 50) ? W[(256 + k) * 800 + g] : 0.f;
    Whp[id] = f2h(v);
    return;
  }
  id -= 409600;
  if (id < 1600) {                       // bcat[dir*800 + c] with same perm; +1 on f gate
    int dirv = id / 800;
    int c = id % 800;
    int n = c >> 2, q = c & 3;
    int g = q * 200 + n;
    bcat[id] = (dirv ? bbv : bfv)[g] + (q == 2 ? 1.f : 0.f);
  }
}

// ---------------- conv2 via rank-1 collapse (6 FMA/elem)
__global__ void conv2_kernel(const float* __restrict__ s, const float* __restrict__ PQ,
                             unsigned short* __restrict__ C2) {
  int row = blockIdx.x;
  int co  = threadIdx.x;
  int t = row & (T_LEN - 1);
  float s0 = s[row];
  float sm = (t > 0)         ? s[row - 1] : 0.f;
  float sp = (t < T_LEN - 1) ? s[row + 1] : 0.f;
  const float* P = PQ;
  const float* Q = PQ + 768;
  float acc = 0.f;
  float a, m;
  a = fmaxf(sm, 0.f); m = fmaxf(-sm, 0.f);
  acc += a * P[0*256+co] + m * Q[0*256+co];
  a = fmaxf(s0, 0.f); m = fmaxf(-s0, 0.f);
  acc += a * P[1*256+co] + m * Q[1*256+co];
  a = fmaxf(sp, 0.f); m = fmaxf(-sp, 0.f);
  acc += a * P[2*256+co] + m * Q[2*256+co];
  C2[(size_t)row * 256 + co] = f2h(fmaxf(acc, 0.f));
}

// ---------------- MFMA GEMM, K=256 fixed. B given TRANSPOSED [n][256].
// mode 0: direct rows; out = relu(acc) + relu(s*k1aw+k1ab)   (conv3+conv1a -> enc)
// mode 2: gathered rows (chain/time-chunk); out = acc + bcat[dir*800+col]
__global__ __launch_bounds__(256, 2) void gemm_kernel(
    const unsigned short* __restrict__ Ag, const unsigned short* __restrict__ Bg0,
    int N, int ntiles, int mode,
    unsigned short* __restrict__ Outp,
    const float* __restrict__ bias, const float* __restrict__ Sg,
    const float* __restrict__ k1aw, const float* __restrict__ k1ab,
    const int* __restrict__ lens, int t0)
{
  __shared__ __align__(16) unsigned short Bl[128*128]; // [n][k-phase], xor-swizzled 16B chunks
  __shared__ __align__(16) unsigned short Al[128*40];  // [m][k32], pad 40 halves
  __shared__ int rowsrc[128];
  int tid = threadIdx.x;
  int tm = blockIdx.x / ntiles, tn = blockIdx.x % ntiles;
  int col0 = tn * 128;
  int lane = tid & 63, wv = tid >> 6;
  int quad = lane >> 4, l16 = lane & 15;
  int wrow = (wv & 1) * 64, wcol = (wv >> 1) * 64;

  int dirv = 0;
  if (mode == 2) dirv = ((tm * 128) >> 8) >> 5;   // chain = m/TB ; dir = chain>>5
  const unsigned short* Bg = Bg0 + (size_t)dirv * 204800;

  if (tid < 128) {
    int r;
    if (mode == 2) {
      int m = tm * 128 + tid;
      int ch = m >> 8;              // TB=256
      int ls = m & 255;
      int b = ch & 31, dd = ch >> 5;
      int L = lens[b]; L = (L < 0) ? 0 : ((L > T_LEN) ? T_LEN : L);
      int t = t0 + ls;
      int src = dd ? (L - 1 - t) : t;
      src = (src < 0) ? 0 : ((src > T_LEN - 1) ? (T_LEN - 1) : src);
      r = b * T_LEN + src;
    } else {
      r = tm * 128 + tid;
    }
    rowsrc[tid] = r;
  }

  floatx4 acc[16];
  #pragma unroll
  for (int i = 0; i < 16; ++i) acc[i] = (floatx4){0.f,0.f,0.f,0.f};

  for (int ph = 0; ph < 2; ++ph) {
    __syncthreads();
    // stage B half-panel from BT: rows n in [col0,col0+128), k in [ph*128, +128)
    #pragma unroll
    for (int it = 0; it < 8; ++it) {
      int idx = it * 256 + tid;             // 2048 b128 chunks
      int n  = idx >> 4;                    // 0..127 local col
      int k8 = idx & 15;                    // 16B chunk within phase
      int nn = col0 + n;
      uint4 v = (uint4){0u,0u,0u,0u};
      if (nn < N) v = *(const uint4*)(Bg + (size_t)nn * 256 + ph * 128 + k8 * 8);
      *(uint4*)(&Bl[n * 128 + ((k8 ^ (n & 7)) * 8)]) = v;
    }
    for (int kb2 = 0; kb2 < 4; ++kb2) {
      int kb = ph * 4 + kb2;
      __syncthreads();
      #pragma unroll
      for (int i = 0; i < 2; ++i) {
        int c2 = i * 256 + tid;
        int r = c2 >> 2, kc = (c2 & 3) * 8;
        uint4 v = *(const uint4*)(Ag + (size_t)rowsrc[r] * 256 + kb * 32 + kc);
        *(uint4*)(&Al[r * 40 + kc]) = v;
      }
      __syncthreads();
      f16x8 af[4], bfr[4];
      #pragma unroll
      for (int mt = 0; mt < 4; ++mt)
        af[mt] = *(const f16x8*)(&Al[(wrow + mt*16 + l16) * 40 + quad * 8]);
      #pragma unroll
      for (int nt = 0; nt < 4; ++nt) {
        int nl = wcol + nt*16 + l16;
        int c = kb2 * 4 + quad;
        bfr[nt] = *(const f16x8*)(&Bl[nl * 128 + ((c ^ (nl & 7)) * 8)]);
      }
      #pragma unroll
      for (int mt = 0; mt < 4; ++mt)
        #pragma unroll
        for (int nt = 0; nt < 4; ++nt)
          acc[mt*4+nt] = __builtin_amdgcn_mfma_f32_16x16x32_f16(af[mt], bfr[nt], acc[mt*4+nt], 0, 0, 0);
    }
  }
  #pragma unroll
  for (int mt = 0; mt < 4; ++mt) {
    #pragma unroll
    for (int nt = 0; nt < 4; ++nt) {
      floatx4 v = acc[mt*4+nt];
      int col = col0 + wcol + nt*16 + l16;
      if (col < N) {
        #pragma unroll
        for (int r = 0; r < 4; ++r) {
          int row = tm * 128 + wrow + mt*16 + quad*4 + r;
          float x = v[r];
          float o;
          if (mode == 0) {
            float sv = Sg[row];
            float a1 = sv * k1aw[col] + k1ab[col];
            o = fmaxf(x, 0.f) + fmaxf(a1, 0.f);
          } else {
            o = x + bias[dirv * 800 + col];
          }
          Outp[(size_t)row * N + col] = f2h(o);
        }
      }
    }
  }
}

// ---------------- chunked persistent recurrent LSTM: one WG per (sample, direction)
// 448 threads; worker tid<400: u = tid>>2 (unit pair 2u,2u+1), s = tid&3 (k-chunk
// [50s,50s+50)). Each worker computes partials of all 8 gates of its 2 units over
// its k-chunk (200 dot2), then a DPP quad butterfly sums the 4 k-splits in-register
// (no LDS, no extra barrier). One barrier per step via double-buffered hbuf.
// h stored in 4 padded 56-half chunks so all reads are aligned b128.
// Weights: 200 dwords/thread from padded Whp (amdgpu_waves_per_eu(2,2) -> 256-reg class).
__global__ __launch_bounds__(448) __attribute__((amdgpu_waves_per_eu(2, 2)))
void lstm_kernel(
    const unsigned short* __restrict__ XWbuf,  // [64][TB][800] f16, cols permuted c=4n+q, bias (+1 f-gate) folded
    const unsigned short* __restrict__ Whp,    // [dir][s][u][q'][64] f16 padded chunks
    const int* __restrict__ lens,
    unsigned short* __restrict__ fwH, unsigned short* __restrict__ bwH,
    float* __restrict__ cState, unsigned short* __restrict__ hState,
    int t0)
{
  int ch  = blockIdx.x;
  int dir = ch >> 5;
  int b   = ch & 31;
  int L = lens[b];
  L = (L < 0) ? 0 : ((L > T_LEN) ? T_LEN : L);
  int tend = t0 + TB; if (tend > L) tend = L;
  int tid = threadIdx.x;
  bool worker = tid < 400;
  int u = tid >> 2;          // unit pair (workers)
  int s = tid & 3;           // k-split chunk (workers)

  __shared__ __align__(16) unsigned short xw_lds[2][SB*800]; // 51.2 KB
  __shared__ __align__(16) unsigned short histb[2][SB*200];  // 12.8 KB
  __shared__ __align__(16) unsigned short hbufs[2][224];     // 4 chunks x 56 halves, x2

  // init hbufs[0] with h state (packed pairs into padded chunks)
  if (t0 > 0) {
    if (tid < 100) {
      unsigned int hv = ((const unsigned int*)(hState + (size_t)ch * HH))[tid];
      *(unsigned int*)&hbufs[0][(tid / 25) * 56 + 2 * (tid % 25)] = hv;
    }
  } else {
    if (tid < 112) ((unsigned int*)&hbufs[0][0])[tid] = 0u;
  }

  float c0 = 0.f, c1 = 0.f;
  unsigned int curh = 0;
  if (worker && t0 > 0) {
    const float* cp = cState + (size_t)ch * HH + 2 * u;
    c0 = cp[0]; c1 = cp[1];
    curh = ((const unsigned int*)(hState + (size_t)ch * HH))[u];
  }

  unsigned int w[200];   // w[q'*25 + d]: q'=2*q+m, d = k-pair within chunk
  if (worker) {
    const unsigned short* Wp = Whp + ((((size_t)dir * 4 + s) * 100 + u) * 8) * 64;
    #pragma unroll
    for (int q = 0; q < 8; ++q) {
      const uint4* wq = (const uint4*)(Wp + q * 64);
      #pragma unroll
      for (int r = 0; r < 6; ++r) {
        uint4 v = wq[r];
        w[q*25 + 4*r + 0] = v.x; w[q*25 + 4*r + 1] = v.y;
        w[q*25 + 4*r + 2] = v.z; w[q*25 + 4*r + 3] = v.w;
      }
      w[q*25 + 24] = *(const unsigned int*)(Wp + q * 64 + 48);
    }
  }

  unsigned short* Hd = dir ? bwH : fwH;
  const unsigned short* XWc = XWbuf + ((size_t)ch * TB) * 800;
  int hoff = (u / 25) * 56 + 2 * (u % 25);   // hbuf write slot for unit pair (loop-invariant)

  // DMA block 0 into xw_lds[0] (16B chunks; wave-uniform base + lane*16)
  if (t0 < tend) {
    #pragma unroll
    for (int it = 0; it < 4; ++it) {
      int cidx = it * 448 + tid;
      if (cidx < 1600)
        GLD_LDS16(XWc + (size_t)cidx * 8, &xw_lds[0][cidx * 8]);
    }
  }
  int buf = 0, cur = 0, hb = 0;
  int prev_tb = -1, prev_cnt = 0;

#define DOT8(d, hv) { \
    ac[0] = dot2f(hv, w[0*25+(d)], ac[0]); ac[1] = dot2f(hv, w[1*25+(d)], ac[1]); \
    ac[2] = dot2f(hv, w[2*25+(d)], ac[2]); ac[3] = dot2f(hv, w[3*25+(d)], ac[3]); \
    ac[4] = dot2f(hv, w[4*25+(d)], ac[4]); ac[5] = dot2f(hv, w[5*25+(d)], ac[5]); \
    ac[6] = dot2f(hv, w[6*25+(d)], ac[6]); ac[7] = dot2f(hv, w[7*25+(d)], ac[7]); }

  for (int tb = t0; tb < tend; tb += SB) {
    int cnt = tend - tb; if (cnt > SB) cnt = SB;
    __syncthreads();   // drains DMA for this block + orders hbuf/hist reuse
    for (int sl = 0; sl < cnt; ++sl) {
      if (sl == 0) {
        // DMA next block into the other buffer (drained by later barriers)
        int ntb = tb + SB;
        if ((ntb - t0) < TB) {
          const unsigned short* src = XWc + (size_t)(ntb - t0) * 800;
          #pragma unroll
          for (int it = 0; it < 4; ++it) {
            int cidx = it * 448 + tid;
            if (cidx < 1600)
              GLD_LDS16(src + (size_t)cidx * 8, &xw_lds[buf ^ 1][cidx * 8]);
          }
        }
        // flush previous block's h history from the OTHER hist buffer (race-free)
        if (prev_tb >= 0) {
          int pcnt = prev_cnt;
          if (tid < pcnt * 25) {
            int srow = dir ? (pcnt - 1 - tid / 25) : (tid / 25);
            uint4 v = *(const uint4*)&histb[hb ^ 1][srow*200 + (tid % 25)*8];
            size_t base = dir ? ((size_t)(b*T_LEN + (L - prev_tb - pcnt)))*HH
                              : ((size_t)(b*T_LEN + prev_tb))*HH;
            *(uint4*)(Hd + base + (size_t)tid*8) = v;
          }
        }
      }
      if (worker) {
        // x-part for our 8 gates: columns 8u..8u+7 (aligned 16B)
        uint4 xv = *(const uint4*)&xw_lds[buf][sl*800 + 8*u];
        const unsigned short* hbp = &hbufs[cur][s * 56];
        const uint4* hp = (const uint4*)hbp;
        float ac[8] = {0.f,0.f,0.f,0.f,0.f,0.f,0.f,0.f};
        uint4 hA = hp[0], hB = hp[1], hC = hp[2];
        DOT8(0,  hA.x) DOT8(1,  hA.y) DOT8(2,  hA.z) DOT8(3,  hA.w)
        DOT8(4,  hB.x) DOT8(5,  hB.y) DOT8(6,  hB.z) DOT8(7,  hB.w)
        DOT8(8,  hC.x) DOT8(9,  hC.y) DOT8(10, hC.z) DOT8(11, hC.w)
        uint4 hD = hp[3], hE = hp[4], hF = hp[5];
        unsigned int hT = *(const unsigned int*)(hbp + 48);
        DOT8(12, hD.x) DOT8(13, hD.y) DOT8(14, hD.z) DOT8(15, hD.w)
        DOT8(16, hE.x) DOT8(17, hE.y) DOT8(18, hE.z) DOT8(19, hE.w)
        DOT8(20, hF.x) DOT8(21, hF.y) DOT8(22, hF.z) DOT8(23, hF.w)
        DOT8(24, hT)
        // quad butterfly: sum the 4 k-split partials (all replicas get the total)
        #pragma unroll
        for (int q = 0; q < 8; ++q) ac[q] = qsum4(ac[q]);
        // add x-part (bias folded; f-gate +1 folded into bcat)
        f16x2 x0 = __builtin_bit_cast(f16x2, xv.x);
        f16x2 x1 = __builtin_bit_cast(f16x2, xv.y);
        f16x2 x2 = __builtin_bit_cast(f16x2, xv.z);
        f16x2 x3 = __builtin_bit_cast(f16x2, xv.w);
        float zi0 = ac[0] + (float)x0[0];
        float zi1 = ac[1] + (float)x2[0];
        float zj0 = ac[2] + (float)x0[1];
        float zj1 = ac[3] + (float)x2[1];
        float zf0 = ac[4] + (float)x1[0];
        float zf1 = ac[5] + (float)x3[0];
        float zo0 = ac[6] + (float)x1[1];
        float zo1 = ac[7] + (float)x3[1];
        c0 = c0 * sigm(zf0) + sigm(zi0) * tanh_fast(zj0);
        c1 = c1 * sigm(zf1) + sigm(zi1) * tanh_fast(zj1);
        float hv0 = tanh_fast(c0) * sigm(zo0);
        float hv1 = tanh_fast(c1) * sigm(zo1);
        curh = (unsigned int)f2h(hv0) | ((unsigned int)f2h(hv1) << 16);
        if (s == 0) {
          *(unsigned int*)&hbufs[cur ^ 1][hoff] = curh;
          *(unsigned int*)&histb[hb][sl*200 + 2*u] = curh;
        }
      }
      cur ^= 1;
      __syncthreads();
    }
    prev_tb = tb; prev_cnt = cnt; buf ^= 1; hb ^= 1;
  }
#undef DOT8
  // final flush + state save
  if (prev_tb >= 0) {
    int pcnt = prev_cnt;
    if (tid < pcnt * 25) {
      int srow = dir ? (pcnt - 1 - tid / 25) : (tid / 25);
      uint4 v = *(const uint4*)&histb[hb ^ 1][srow*200 + (tid % 25)*8];
      size_t base = dir ? ((size_t)(b*T_LEN + (L - prev_tb - pcnt)))*HH
                        : ((size_t)(b*T_LEN + prev_tb))*HH;
      *(uint4*)(Hd + base + (size_t)tid*8) = v;
    }
  }
  if (worker && s == 0) {
    float* cp = cState + (size_t)ch * HH + 2 * u;
    cp[0] = c0; cp[1] = c1;
    ((unsigned int*)(hState + (size_t)ch * HH))[u] = curh;
  }
}

// ---------------- logits = [fwH|bwH] @ Wd + bd
__global__ __launch_bounds__(256) void out_kernel(
    const unsigned short* __restrict__ fwH, const unsigned short* __restrict__ bwH,
    const float* __restrict__ Wd, const float* __restrict__ bd, float* __restrict__ out)
{
  __shared__ float wd[2000];
  int tid = threadIdx.x;
  for (int i = tid; i < 2000; i += 256) wd[i] = Wd[i];
  __syncthreads();
  int row = blockIdx.x * 256 + tid;
  float acc0 = bd[0], acc1 = bd[1], acc2 = bd[2], acc3 = bd[3], acc4 = bd[4];
  const unsigned int* fu = (const unsigned int*)(fwH + (size_t)row * HH);
  const unsigned int* bu = (const unsigned int*)(bwH + (size_t)row * HH);
  #pragma unroll 4
  for (int i = 0; i < 100; ++i) {
    f16x2 pf = __builtin_bit_cast(f16x2, fu[i]);
    f16x2 pb = __builtin_bit_cast(f16x2, bu[i]);
    int k = 2 * i;
    float f0 = (float)pf[0], f1 = (float)pf[1];
    float b0 = (float)pb[0], b1 = (float)pb[1];
    const float* w0 = &wd[k*5];
    const float* w1 = &wd[(k+1)*5];
    const float* w2 = &wd[(200+k)*5];
    const float* w3 = &wd[(201+k)*5];
    acc0 += f0*w0[0] + f1*w1[0] + b0*w2[0] + b1*w3[0];
    acc1 += f0*w0[1] + f1*w1[1] + b0*w2[1] + b1*w3[1];
    acc2 += f0*w0[2] + f1*w1[2] + b0*w2[2] + b1*w3[2];
    acc3 += f0*w0[3] + f1*w1[3] + b0*w2[3] + b1*w3[3];
    acc4 += f0*w0[4] + f1*w1[4] + b0*w2[4] + b1*w3[4];
  }
  float* o = out + (size_t)row * 5;
  o[0]=acc0; o[1]=acc1; o[2]=acc2; o[3]=acc3; o[4]=acc4;
}

extern "C" void kernel_launch(void* const* d_in, const int* in_sizes, int n_in,
                              void* d_out, int out_size, void* d_ws, size_t ws_size,
                              hipStream_t stream)
{
  const float* signals = (const float*)d_in[0];
  const int*   lens    = (const int*)  d_in[1];
  const float* k1w     = (const float*)d_in[2];
  const float* k1aw    = (const float*)d_in[3];
  const float* k1ab    = (const float*)d_in[4];
  const float* k2w     = (const float*)d_in[5];
  const float* k3w     = (const float*)d_in[6];
  const float* Wf      = (const float*)d_in[7];
  const float* bf      = (const float*)d_in[8];
  const float* Wb      = (const float*)d_in[9];
  const float* bb      = (const float*)d_in[10];
  const float* Wd      = (const float*)d_in[11];
  const float* bd      = (const float*)d_in[12];
  float* out = (float*)d_out;
  char* ws = (char*)d_ws;

  // Region A aliases C2 (conv phase) and XWbuf (LSTM phase) — disjoint lifetimes.
  size_t szC2   = (size_t)NROWS * 256 * 2;          // 33,554,432
  size_t szXWb  = (size_t)64 * TB * 800 * 2;        // 26,214,400
  size_t szA    = (szC2 > szXWb) ? szC2 : szXWb;
  size_t oA   = 0;
  size_t oE   = oA   + szA;
  size_t oFw  = oE   + (size_t)NROWS*256*2;
  size_t oBw  = oFw  + (size_t)NROWS*HH*2;
  size_t oWhp = oBw  + (size_t)NROWS*HH*2;
  size_t oWx2 = oWhp + (size_t)2*4*100*8*64*2;      // 819,200
  size_t oK3  = oWx2 + (size_t)2*256*800*2;
  size_t oPQ  = oK3  + (size_t)256*256*2;
  size_t oBc  = oPQ  + 1536*4;
  size_t oCst = oBc  + 1600*4;
  size_t oHst = oCst + (size_t)64*HH*4;
  size_t total= oHst + (size_t)64*HH*2;             // ~115.8 MiB
  if (ws_size < total) return;

  unsigned short* C2    = (unsigned short*)(ws + oA);
  unsigned short* XWbuf = (unsigned short*)(ws + oA);
  unsigned short* E     = (unsigned short*)(ws + oE);
  unsigned short* fwH   = (unsigned short*)(ws + oFw);
  unsigned short* bwH   = (unsigned short*)(ws + oBw);
  unsigned short* Whp   = (unsigned short*)(ws + oWhp);
  unsigned short* Wx2   = (unsigned short*)(ws + oWx2);
  unsigned short* K3h   = (unsigned short*)(ws + oK3);
  float* PQ     = (float*)(ws + oPQ);
  float* bcat   = (float*)(ws + oBc);
  float* cState = (float*)(ws + oCst);
  unsigned short* hState = (unsigned short*)(ws + oHst);

  hipMemsetAsync(fwH, 0, (size_t)2*NROWS*HH*2, stream);
  pq_kernel  <<<6,     256, 0, stream>>>(k1w, k2w, PQ);
  prep_kernel<<<3463,  256, 0, stream>>>(k3w, Wf, bf, Wb, bb, K3h, Wx2, Whp, bcat);
  conv2_kernel<<<NROWS, 256, 0, stream>>>(signals, PQ, C2);
  gemm_kernel<<<1024,  256, 0, stream>>>(C2, K3h, 256, 2, 0, E, nullptr, signals, k1aw, k1ab, nullptr, 0);
  for (int t0 = 0; t0 < T_LEN; t0 += TB) {
    gemm_kernel<<<896, 256, 0, stream>>>(E, Wx2, 800, 7, 2, XWbuf, bcat, nullptr, nullptr, nullptr, lens, t0);
    lstm_kernel<<<64,  448, 0, stream>>>(XWbuf, Whp, lens, fwH, bwH, cState, hState, t0);
  }
  out_kernel <<<256,   256, 0, stream>>>(fwH, bwH, Wd, bd, out);
}

// Round 4
// 2925.876 us; speedup vs baseline: 1.1116x; 1.1116x over previous
//
#include <hip/hip_runtime.h>
#include <cstdint>

#define T_LEN 2048
#define NB    32
#define NROWS (NB*T_LEN)   // 65536
#define HH    200
#define G4    800
#define TB    256          // LSTM time-chunk (per dispatch)
#define SB    8            // step block staged in LDS

typedef _Float16 f16;
typedef _Float16 f16x2 __attribute__((ext_vector_type(2)));
typedef _Float16 f16x8 __attribute__((ext_vector_type(8)));
typedef float   floatx4 __attribute__((ext_vector_type(4)));

#define GLD_LDS16(g, l) __builtin_amdgcn_global_load_lds( \
    (const __attribute__((address_space(1))) void*)(g), \
    (__attribute__((address_space(3))) void*)(l), 16, 0, 0)

static __device__ __forceinline__ unsigned short f2h(float x) {
  f16 h = (f16)x; return __builtin_bit_cast(unsigned short, h);
}
static __device__ __forceinline__ float sigm(float x) {
  return __builtin_amdgcn_rcpf(1.f + __expf(-x));
}
static __device__ __forceinline__ float tanh_fast(float x) {
  return 1.f - 2.f * __builtin_amdgcn_rcpf(__expf(2.f * x) + 1.f);
}
// h-image half-offset for unit n: B-fragment image of 16x16x32 col 0
// (k-tile kt=n>>5 at kt*512; k-group kg=(n>>3)&3 at kg*128; j=n&7)
static __device__ __forceinline__ int h_off(int n) {
  return (n >> 5) * 512 + ((n >> 3) & 3) * 128 + (n & 7);
}

// ---------------- P/Q precompute: P[dt,co]=sum_ci relu(k1)k2, Q with relu(-k1)
__global__ void pq_kernel(const float* __restrict__ k1w, const float* __restrict__ k2w,
                          float* __restrict__ PQ) {
  int id = blockIdx.x * 256 + threadIdx.x;   // 1536 total
  int pq = id / 768;
  int rem = id % 768;
  int wdt = rem / 256;
  int co  = rem % 256;
  float acc = 0.f;
  for (int ci = 0; ci < 256; ++ci) {
    float k = k1w[ci];
    float kk = pq ? fmaxf(-k, 0.f) : fmaxf(k, 0.f);
    acc += kk * k2w[((size_t)wdt * 256 + ci) * 256 + co];
  }
  PQ[id] = acc;
}

// ---------------- f16 weight prep (B matrices stored TRANSPOSED: [n][k])
// K3T[co][ci] ; Wx2[dir][c][k] with permuted col c=4n+q (gate g=q*200+n) ;
// WhA: per-lane MFMA A-fragments of Wh^T, [dir][ct<56][lane<64][28 dwords]
//   (ct = 16-gate-col tile; dwords 4*kt..4*kt+3 = k-tile kt<7 of 16x16x32 frags,
//    K padded 200->224 with zeros; col-tiles ct>=50 are zero) ;
// bcat permuted, f-gate +1 folded.
__global__ void prep_kernel(const float* __restrict__ k3w,
                            const float* __restrict__ Wf, const float* __restrict__ bfv,
                            const float* __restrict__ Wb, const float* __restrict__ bbv,
                            unsigned short* __restrict__ K3h, unsigned short* __restrict__ Wx2,
                            unsigned short* __restrict__ WhA, float* __restrict__ bcat) {
  int id = blockIdx.x * 256 + threadIdx.x;
  if (id < 65536) {                      // K3T[co*256+ci] = k3w[ci*256+co]
    K3h[id] = f2h(k3w[(id & 255) * 256 + (id >> 8)]);
    return;
  }
  id -= 65536;
  if (id < 409600) {                     // Wx2[dir][c<800][k<256]
    int dirv = id / 204800;
    int r = id % 204800;
    int c = r >> 8, k = r & 255;
    int n = c >> 2, q = c & 3;
    int g = q * 200 + n;
    const float* W = dirv ? Wb : Wf;
    Wx2[id] = f2h(W[k * 800 + g]);
    return;
  }
  id -= 409600;
  if (id < 401408) {                     // WhA halves: 2*56*64*28*2
    int hi = id & 1;
    int d  = id >> 1;                    // dword index
    int r  = d % 28;
    int t2 = d / 28;
    int lane = t2 & 63;
    int t3 = t2 >> 6;
    int ct = t3 % 56;
    int dirv = t3 / 56;
    int row = lane & 15;
    int kg  = lane >> 4;
    int c = ct * 16 + row;
    float v = 0.f;
    if (c < 800) {
      int kt = r >> 2;                   // 0..6
      int k = kt * 32 + kg * 8 + (r & 3) * 2 + hi;
      if (k < 200) {
        int n = c >> 2, q = c & 3;
        int g = q * 200 + n;
        const float* W = dirv ? Wb : Wf;
        v = W[(256 + k) * 800 + g];
      }
    }
    WhA[id] = f2h(v);
    return;
  }
  id -= 401408;
  if (id < 1600) {                       // bcat[dir*800 + c] with same perm; +1 on f gate
    int dirv = id / 800;
    int c = id % 800;
    int n = c >> 2, q = c & 3;
    int g = q * 200 + n;
    bcat[id] = (dirv ? bbv : bfv)[g] + (q == 2 ? 1.f : 0.f);
  }
}

// ---------------- conv2 via rank-1 collapse (6 FMA/elem)
__global__ void conv2_kernel(const float* __restrict__ s, const float* __restrict__ PQ,
                             unsigned short* __restrict__ C2) {
  int row = blockIdx.x;
  int co  = threadIdx.x;
  int t = row & (T_LEN - 1);
  float s0 = s[row];
  float sm = (t > 0)         ? s[row - 1] : 0.f;
  float sp = (t < T_LEN - 1) ? s[row + 1] : 0.f;
  const float* P = PQ;
  const float* Q = PQ + 768;
  float acc = 0.f;
  float a, m;
  a = fmaxf(sm, 0.f); m = fmaxf(-sm, 0.f);
  acc += a * P[0*256+co] + m * Q[0*256+co];
  a = fmaxf(s0, 0.f); m = fmaxf(-s0, 0.f);
  acc += a * P[1*256+co] + m * Q[1*256+co];
  a = fmaxf(sp, 0.f); m = fmaxf(-sp, 0.f);
  acc += a * P[2*256+co] + m * Q[2*256+co];
  C2[(size_t)row * 256 + co] = f2h(fmaxf(acc, 0.f));
}

// ---------------- MFMA GEMM, K=256 fixed. B given TRANSPOSED [n][256].
// mode 0: direct rows; out = relu(acc) + relu(s*k1aw+k1ab)   (conv3+conv1a -> enc)
// mode 2: gathered rows (chain/time-chunk); out = acc + bcat[dir*800+col]
__global__ __launch_bounds__(256, 2) void gemm_kernel(
    const unsigned short* __restrict__ Ag, const unsigned short* __restrict__ Bg0,
    int N, int ntiles, int mode,
    unsigned short* __restrict__ Outp,
    const float* __restrict__ bias, const float* __restrict__ Sg,
    const float* __restrict__ k1aw, const float* __restrict__ k1ab,
    const int* __restrict__ lens, int t0)
{
  __shared__ __align__(16) unsigned short Bl[128*128]; // [n][k-phase], xor-swizzled 16B chunks
  __shared__ __align__(16) unsigned short Al[128*40];  // [m][k32], pad 40 halves
  __shared__ int rowsrc[128];
  int tid = threadIdx.x;
  int tm = blockIdx.x / ntiles, tn = blockIdx.x % ntiles;
  int col0 = tn * 128;
  int lane = tid & 63, wv = tid >> 6;
  int quad = lane >> 4, l16 = lane & 15;
  int wrow = (wv & 1) * 64, wcol = (wv >> 1) * 64;

  int dirv = 0;
  if (mode == 2) dirv = ((tm * 128) >> 8) >> 5;   // chain = m/TB ; dir = chain>>5
  const unsigned short* Bg = Bg0 + (size_t)dirv * 204800;

  if (tid < 128) {
    int r;
    if (mode == 2) {
      int m = tm * 128 + tid;
      int ch = m >> 8;              // TB=256
      int ls = m & 255;
      int b = ch & 31, dd = ch >> 5;
      int L = lens[b]; L = (L < 0) ? 0 : ((L > T_LEN) ? T_LEN : L);
      int t = t0 + ls;
      int src = dd ? (L - 1 - t) : t;
      src = (src < 0) ? 0 : ((src > T_LEN - 1) ? (T_LEN - 1) : src);
      r = b * T_LEN + src;
    } else {
      r = tm * 128 + tid;
    }
    rowsrc[tid] = r;
  }

  floatx4 acc[16];
  #pragma unroll
  for (int i = 0; i < 16; ++i) acc[i] = (floatx4){0.f,0.f,0.f,0.f};

  for (int ph = 0; ph < 2; ++ph) {
    __syncthreads();
    // stage B half-panel from BT: rows n in [col0,col0+128), k in [ph*128, +128)
    #pragma unroll
    for (int it = 0; it < 8; ++it) {
      int idx = it * 256 + tid;             // 2048 b128 chunks
      int n  = idx >> 4;                    // 0..127 local col
      int k8 = idx & 15;                    // 16B chunk within phase
      int nn = col0 + n;
      uint4 v = (uint4){0u,0u,0u,0u};
      if (nn < N) v = *(const uint4*)(Bg + (size_t)nn * 256 + ph * 128 + k8 * 8);
      *(uint4*)(&Bl[n * 128 + ((k8 ^ (n & 7)) * 8)]) = v;
    }
    for (int kb2 = 0; kb2 < 4; ++kb2) {
      int kb = ph * 4 + kb2;
      __syncthreads();
      #pragma unroll
      for (int i = 0; i < 2; ++i) {
        int c2 = i * 256 + tid;
        int r = c2 >> 2, kc = (c2 & 3) * 8;
        uint4 v = *(const uint4*)(Ag + (size_t)rowsrc[r] * 256 + kb * 32 + kc);
        *(uint4*)(&Al[r * 40 + kc]) = v;
      }
      __syncthreads();
      f16x8 af[4], bfr[4];
      #pragma unroll
      for (int mt = 0; mt < 4; ++mt)
        af[mt] = *(const f16x8*)(&Al[(wrow + mt*16 + l16) * 40 + quad * 8]);
      #pragma unroll
      for (int nt = 0; nt < 4; ++nt) {
        int nl = wcol + nt*16 + l16;
        int c = kb2 * 4 + quad;
        bfr[nt] = *(const f16x8*)(&Bl[nl * 128 + ((c ^ (nl & 7)) * 8)]);
      }
      #pragma unroll
      for (int mt = 0; mt < 4; ++mt)
        #pragma unroll
        for (int nt = 0; nt < 4; ++nt)
          acc[mt*4+nt] = __builtin_amdgcn_mfma_f32_16x16x32_f16(af[mt], bfr[nt], acc[mt*4+nt], 0, 0, 0);
    }
  }
  #pragma unroll
  for (int mt = 0; mt < 4; ++mt) {
    #pragma unroll
    for (int nt = 0; nt < 4; ++nt) {
      floatx4 v = acc[mt*4+nt];
      int col = col0 + wcol + nt*16 + l16;
      if (col < N) {
        #pragma unroll
        for (int r = 0; r < 4; ++r) {
          int row = tm * 128 + wrow + mt*16 + quad*4 + r;
          float x = v[r];
          float o;
          if (mode == 0) {
            float sv = Sg[row];
            float a1 = sv * k1aw[col] + k1ab[col];
            o = fmaxf(x, 0.f) + fmaxf(a1, 0.f);
          } else {
            o = x + bias[dirv * 800 + col];
          }
          Outp[(size_t)row * N + col] = f2h(o);
        }
      }
    }
  }
}

// ---------------- MFMA recurrent LSTM: one WG per (sample, direction), 512 thr (8 waves)
// Per step: z[800] = WhT[800x200] @ h[200] on the MATRIX pipe.
//   A = WhT tiles (rows = permuted gate-cols c=4n+q), B = h in col 0 (cols 1-15 zero),
//   7x 16x16x32 f16 MFMA per tile (K padded 200->224). 56 col-tiles (50 real), 7/wave.
// D col-0 lanes (l&15==0) hold ALL FOUR gates of one unit in their 4 accum regs ->
//   z round-trips through a 3.6KB LDS buffer; 200 act lanes do 1x-redundant activation.
// Weights persist in registers: 7x28=196 VGPR/thread. h lives in LDS as a B-fragment
//   image (zeros pre-baked for lanes l&15!=0 and k>=200), rebuilt per step by b16 writes.
__global__ __launch_bounds__(512, 2)
void lstm_kernel(
    const unsigned short* __restrict__ XWbuf,  // [64][TB][800] f16, cols c=4n+q, bias(+1 f) folded
    const unsigned short* __restrict__ WhA,    // per-lane A-fragments (see prep)
    const int* __restrict__ lens,
    unsigned short* __restrict__ fwH, unsigned short* __restrict__ bwH,
    float* __restrict__ cState, unsigned short* __restrict__ hState,
    int t0)
{
  int ch  = blockIdx.x;
  int dir = ch >> 5;
  int b   = ch & 31;
  int L = lens[b];
  L = (L < 0) ? 0 : ((L > T_LEN) ? T_LEN : L);
  int tend = t0 + TB; if (tend > L) tend = L;
  int tid = threadIdx.x;
  int lane = tid & 63, w = tid >> 6;
  int p4 = lane >> 4;
  bool zlane = (lane & 15) == 0;

  __shared__ __align__(16) unsigned short xw_lds[2][SB*800]; // 25.6 KB
  __shared__ __align__(16) unsigned short hist[SB*200];      // 3.2 KB
  __shared__ __align__(16) unsigned short himg[3584];        // 7 KB B-frag image of h
  __shared__ __align__(16) float zbuf[224*4];                // 3.6 KB z scratch

  // zero the h image (bakes the zero cols 1-15 of B and the k>=200 pad)
  for (int i = tid; i < 1792; i += 512) ((unsigned int*)himg)[i] = 0u;

  float c = 0.f;
  unsigned short last_h = 0;
  if (tid < 200 && t0 > 0) {
    c = cState[ch * HH + tid];
    last_h = hState[ch * HH + tid];
  }
  __syncthreads();
  if (tid < 200 && t0 > 0) himg[h_off(tid)] = last_h;

  // load persistent A-fragments (7 col-tiles per wave; ct>=50 are zero dummies)
  f16x8 WA[7][7];
  #pragma unroll
  for (int i = 0; i < 7; ++i) {
    const uint4* wp = (const uint4*)WhA + ((size_t)((dir * 56 + (w * 7 + i)) * 64 + lane)) * 7;
    #pragma unroll
    for (int kt = 0; kt < 7; ++kt)
      WA[i][kt] = __builtin_bit_cast(f16x8, wp[kt]);
  }

  unsigned short* Hd = dir ? bwH : fwH;
  const unsigned short* XWc = XWbuf + ((size_t)ch * TB) * 800;

  // DMA block 0 into xw_lds[0]
  if (t0 < tend) {
    #pragma unroll
    for (int it = 0; it < 2; ++it) {
      int cidx = it * 512 + tid;
      if (cidx < 800)
        GLD_LDS16(XWc + (size_t)cidx * 8, &xw_lds[0][cidx * 8]);
    }
  }
  __syncthreads();   // h image (incl. state write) visible to all B-frag readers

  int buf = 0;
  int prev_tb = -1, prev_cnt = 0;
  int ctb = w * 7;

  for (int tb = t0; tb < tend; tb += SB) {
    int cnt = tend - tb; if (cnt > SB) cnt = SB;
    for (int sl = 0; sl < cnt; ++sl) {
      if (sl == 0) {
        // DMA next block into the other buffer (drains at a later barrier)
        int ntb = tb + SB;
        if ((ntb - t0) < TB) {
          const unsigned short* src = XWc + (size_t)(ntb - t0) * 800;
          #pragma unroll
          for (int it = 0; it < 2; ++it) {
            int cidx = it * 512 + tid;
            if (cidx < 800)
              GLD_LDS16(src + (size_t)cidx * 8, &xw_lds[buf ^ 1][cidx * 8]);
          }
        }
        // flush previous block's h history (reads drain at barrier 1 before rewrites)
        if (prev_tb >= 0) {
          int pcnt = prev_cnt;
          if (tid < pcnt * 25) {
            int srow = dir ? (pcnt - 1 - tid / 25) : (tid / 25);
            uint4 v = *(const uint4*)&hist[srow*200 + (tid % 25)*8];
            size_t base = dir ? ((size_t)(b*T_LEN + (L - prev_tb - pcnt)))*HH
                              : ((size_t)(b*T_LEN + prev_tb))*HH;
            *(uint4*)(Hd + base + (size_t)tid*8) = v;
          }
        }
      }
      // B fragments of h (conflict-free b128 reads of the image)
      f16x8 hb[7];
      #pragma unroll
      for (int kt = 0; kt < 7; ++kt)
        hb[kt] = *(const f16x8*)(himg + kt * 512 + lane * 8);

      // MFMA: 7 col-tiles, paired for ILP
      #pragma unroll
      for (int pr = 0; pr < 3; ++pr) {
        floatx4 C0 = (floatx4){0.f,0.f,0.f,0.f};
        floatx4 C1 = (floatx4){0.f,0.f,0.f,0.f};
        #pragma unroll
        for (int kt = 0; kt < 7; ++kt) {
          C0 = __builtin_amdgcn_mfma_f32_16x16x32_f16(WA[2*pr  ][kt], hb[kt], C0, 0, 0, 0);
          C1 = __builtin_amdgcn_mfma_f32_16x16x32_f16(WA[2*pr+1][kt], hb[kt], C1, 0, 0, 0);
        }
        if (zlane) {
          *(floatx4*)&zbuf[((ctb + 2*pr    ) * 4 + p4) * 4] = C0;
          *(floatx4*)&zbuf[((ctb + 2*pr + 1) * 4 + p4) * 4] = C1;
        }
      }
      {
        floatx4 C0 = (floatx4){0.f,0.f,0.f,0.f};
        #pragma unroll
        for (int kt = 0; kt < 7; ++kt)
          C0 = __builtin_amdgcn_mfma_f32_16x16x32_f16(WA[6][kt], hb[kt], C0, 0, 0, 0);
        if (zlane)
          *(floatx4*)&zbuf[((ctb + 6) * 4 + p4) * 4] = C0;
      }
      __syncthreads();   // z visible; h-frag regs already loaded -> image rewrite safe
      if (tid < 200) {
        floatx4 z = *(const floatx4*)&zbuf[tid * 4];
        uint2 xv = *(const uint2*)&xw_lds[buf][sl*800 + 4*tid];
        f16x2 xa = __builtin_bit_cast(f16x2, xv.x);
        f16x2 xb = __builtin_bit_cast(f16x2, xv.y);
        float zi = z[0] + (float)xa[0];
        float zj = z[1] + (float)xa[1];
        float zf = z[2] + (float)xb[0];
        float zo = z[3] + (float)xb[1];
        c = c * sigm(zf) + sigm(zi) * tanh_fast(zj);
        float h = tanh_fast(c) * sigm(zo);
        unsigned short hh = f2h(h);
        last_h = hh;
        himg[h_off(tid)] = hh;
        hist[sl*200 + tid] = hh;
      }
      __syncthreads();   // new h visible for next step
    }
    prev_tb = tb; prev_cnt = cnt; buf ^= 1;
  }
  // final flush + state save
  if (prev_tb >= 0) {
    int pcnt = prev_cnt;
    if (tid < pcnt * 25) {
      int srow = dir ? (pcnt - 1 - tid / 25) : (tid / 25);
      uint4 v = *(const uint4*)&hist[srow*200 + (tid % 25)*8];
      size_t base = dir ? ((size_t)(b*T_LEN + (L - prev_tb - pcnt)))*HH
                        : ((size_t)(b*T_LEN + prev_tb))*HH;
      *(uint4*)(Hd + base + (size_t)tid*8) = v;
    }
  }
  if (tid < 200) {
    cState[ch * HH + tid] = c;
    hState[ch * HH + tid] = last_h;
  }
}

// ---------------- logits = [fwH|bwH] @ Wd + bd
__global__ __launch_bounds__(256) void out_kernel(
    const unsigned short* __restrict__ fwH, const unsigned short* __restrict__ bwH,
    const float* __restrict__ Wd, const float* __restrict__ bd, float* __restrict__ out)
{
  __shared__ float wd[2000];
  int tid = threadIdx.x;
  for (int i = tid; i < 2000; i += 256) wd[i] = Wd[i];
  __syncthreads();
  int row = blockIdx.x * 256 + tid;
  float acc0 = bd[0], acc1 = bd[1], acc2 = bd[2], acc3 = bd[3], acc4 = bd[4];
  const unsigned int* fu = (const unsigned int*)(fwH + (size_t)row * HH);
  const unsigned int* bu = (const unsigned int*)(bwH + (size_t)row * HH);
  #pragma unroll 4
  for (int i = 0; i < 100; ++i) {
    f16x2 pf = __builtin_bit_cast(f16x2, fu[i]);
    f16x2 pb = __builtin_bit_cast(f16x2, bu[i]);
    int k = 2 * i;
    float f0 = (float)pf[0], f1 = (float)pf[1];
    float b0 = (float)pb[0], b1 = (float)pb[1];
    const float* w0 = &wd[k*5];
    const float* w1 = &wd[(k+1)*5];
    const float* w2 = &wd[(200+k)*5];
    const float* w3 = &wd[(201+k)*5];
    acc0 += f0*w0[0] + f1*w1[0] + b0*w2[0] + b1*w3[0];
    acc1 += f0*w0[1] + f1*w1[1] + b0*w2[1] + b1*w3[1];
    acc2 += f0*w0[2] + f1*w1[2] + b0*w2[2] + b1*w3[2];
    acc3 += f0*w0[3] + f1*w1[3] + b0*w2[3] + b1*w3[3];
    acc4 += f0*w0[4] + f1*w1[4] + b0*w2[4] + b1*w3[4];
  }
  float* o = out + (size_t)row * 5;
  o[0]=acc0; o[1]=acc1; o[2]=acc2; o[3]=acc3; o[4]=acc4;
}

extern "C" void kernel_launch(void* const* d_in, const int* in_sizes, int n_in,
                              void* d_out, int out_size, void* d_ws, size_t ws_size,
                              hipStream_t stream)
{
  const float* signals = (const float*)d_in[0];
  const int*   lens    = (const int*)  d_in[1];
  const float* k1w     = (const float*)d_in[2];
  const float* k1aw    = (const float*)d_in[3];
  const float* k1ab    = (const float*)d_in[4];
  const float* k2w     = (const float*)d_in[5];
  const float* k3w     = (const float*)d_in[6];
  const float* Wf      = (const float*)d_in[7];
  const float* bf      = (const float*)d_in[8];
  const float* Wb      = (const float*)d_in[9];
  const float* bb      = (const float*)d_in[10];
  const float* Wd      = (const float*)d_in[11];
  const float* bd      = (const float*)d_in[12];
  float* out = (float*)d_out;
  char* ws = (char*)d_ws;

  // Region A aliases C2 (conv phase) and XWbuf (LSTM phase) — disjoint lifetimes.
  size_t szC2   = (size_t)NROWS * 256 * 2;          // 33,554,432
  size_t szXWb  = (size_t)64 * TB * 800 * 2;        // 26,214,400
  size_t szA    = (szC2 > szXWb) ? szC2 : szXWb;
  size_t oA   = 0;
  size_t oE   = oA   + szA;
  size_t oFw  = oE   + (size_t)NROWS*256*2;
  size_t oBw  = oFw  + (size_t)NROWS*HH*2;
  size_t oWhA = oBw  + (size_t)NROWS*HH*2;
  size_t oWx2 = oWhA + (size_t)2*56*64*28*4;        // 802,816
  size_t oK3  = oWx2 + (size_t)2*256*800*2;
  size_t oPQ  = oK3  + (size_t)256*256*2;
  size_t oBc  = oPQ  + 1536*4;
  size_t oCst = oBc  + 1600*4;
  size_t oHst = oCst + (size_t)64*HH*4;
  size_t total= oHst + (size_t)64*HH*2;
  if (ws_size < total) return;

  unsigned short* C2    = (unsigned short*)(ws + oA);
  unsigned short* XWbuf = (unsigned short*)(ws + oA);
  unsigned short* E     = (unsigned short*)(ws + oE);
  unsigned short* fwH   = (unsigned short*)(ws + oFw);
  unsigned short* bwH   = (unsigned short*)(ws + oBw);
  unsigned short* WhA   = (unsigned short*)(ws + oWhA);
  unsigned short* Wx2   = (unsigned short*)(ws + oWx2);
  unsigned short* K3h   = (unsigned short*)(ws + oK3);
  float* PQ     = (float*)(ws + oPQ);
  float* bcat   = (float*)(ws + oBc);
  float* cState = (float*)(ws + oCst);
  unsigned short* hState = (unsigned short*)(ws + oHst);

  (void)hipMemsetAsync(fwH, 0, (size_t)2*NROWS*HH*2, stream);
  pq_kernel  <<<6,     256, 0, stream>>>(k1w, k2w, PQ);
  prep_kernel<<<3431,  256, 0, stream>>>(k3w, Wf, bf, Wb, bb, K3h, Wx2, WhA, bcat);
  conv2_kernel<<<NROWS, 256, 0, stream>>>(signals, PQ, C2);
  gemm_kernel<<<1024,  256, 0, stream>>>(C2, K3h, 256, 2, 0, E, nullptr, signals, k1aw, k1ab, nullptr, 0);
  for (int t0 = 0; t0 < T_LEN; t0 += TB) {
    gemm_kernel<<<896, 256, 0, stream>>>(E, Wx2, 800, 7, 2, XWbuf, bcat, nullptr, nullptr, nullptr, lens, t0);
    lstm_kernel<<<64,  512, 0, stream>>>(XWbuf, WhA, lens, fwH, bwH, cState, hState, t0);
  }
  out_kernel <<<256,   256, 0, stream>>>(fwH, bwH, Wd, bd, out);
}

// Round 5
// 2868.783 us; speedup vs baseline: 1.1338x; 1.0199x over previous
//
#include <hip/hip_runtime.h>
#include <cstdint>

#define T_LEN 2048
#define NB    32
#define NROWS (NB*T_LEN)   // 65536
#define HH    200
#define G4    800
#define TB    256          // LSTM time-chunk (per dispatch)
#define SB    8            // step block staged in LDS

typedef _Float16 f16;
typedef _Float16 f16x2 __attribute__((ext_vector_type(2)));
typedef _Float16 f16x8 __attribute__((ext_vector_type(8)));
typedef float   floatx4 __attribute__((ext_vector_type(4)));

#define GLD_LDS16(g, l) __builtin_amdgcn_global_load_lds( \
    (const __attribute__((address_space(1))) void*)(g), \
    (__attribute__((address_space(3))) void*)(l), 16, 0, 0)

static __device__ __forceinline__ unsigned short f2h(float x) {
  f16 h = (f16)x; return __builtin_bit_cast(unsigned short, h);
}
static __device__ __forceinline__ float sigm(float x) {
  return __builtin_amdgcn_rcpf(1.f + __expf(-x));
}
static __device__ __forceinline__ float tanh_fast(float x) {
  return 1.f - 2.f * __builtin_amdgcn_rcpf(__expf(2.f * x) + 1.f);
}

// ---------------- P/Q precompute: P[dt,co]=sum_ci relu(k1)k2, Q with relu(-k1)
__global__ void pq_kernel(const float* __restrict__ k1w, const float* __restrict__ k2w,
                          float* __restrict__ PQ) {
  int id = blockIdx.x * 256 + threadIdx.x;   // 1536 total
  int pq = id / 768;
  int rem = id % 768;
  int wdt = rem / 256;
  int co  = rem % 256;
  float acc = 0.f;
  for (int ci = 0; ci < 256; ++ci) {
    float k = k1w[ci];
    float kk = pq ? fmaxf(-k, 0.f) : fmaxf(k, 0.f);
    acc += kk * k2w[((size_t)wdt * 256 + ci) * 256 + co];
  }
  PQ[id] = acc;
}

// ---------------- f16 weight prep (B matrices stored TRANSPOSED: [n][k])
// K3T[co][ci] ; Wx2[dir][c][k] with permuted col c=4n+q (gate g=q*200+n) ;
// WhA: per-lane MFMA A-fragments of Wh^T, [dir][ct<56][lane<64][28 dwords]
//   (ct = 16-gate-col tile; dwords 4*kt..4*kt+3 = k-tile kt<7 of 16x16x32 frags,
//    K padded 200->224 with zeros; col-tiles ct>=50 are zero) ;
// bcat permuted, f-gate +1 folded.
__global__ void prep_kernel(const float* __restrict__ k3w,
                            const float* __restrict__ Wf, const float* __restrict__ bfv,
                            const float* __restrict__ Wb, const float* __restrict__ bbv,
                            unsigned short* __restrict__ K3h, unsigned short* __restrict__ Wx2,
                            unsigned short* __restrict__ WhA, float* __restrict__ bcat) {
  int id = blockIdx.x * 256 + threadIdx.x;
  if (id < 65536) {                      // K3T[co*256+ci] = k3w[ci*256+co]
    K3h[id] = f2h(k3w[(id & 255) * 256 + (id >> 8)]);
    return;
  }
  id -= 65536;
  if (id < 409600) {                     // Wx2[dir][c<800][k<256]
    int dirv = id / 204800;
    int r = id % 204800;
    int c = r >> 8, k = r & 255;
    int n = c >> 2, q = c & 3;
    int g = q * 200 + n;
    const float* W = dirv ? Wb : Wf;
    Wx2[id] = f2h(W[k * 800 + g]);
    return;
  }
  id -= 409600;
  if (id < 401408) {                     // WhA halves: 2*56*64*28*2
    int hi = id & 1;
    int d  = id >> 1;                    // dword index
    int r  = d % 28;
    int t2 = d / 28;
    int lane = t2 & 63;
    int t3 = t2 >> 6;
    int ct = t3 % 56;
    int dirv = t3 / 56;
    int row = lane & 15;
    int kg  = lane >> 4;
    int c = ct * 16 + row;
    float v = 0.f;
    if (c < 800) {
      int kt = r >> 2;                   // 0..6
      int k = kt * 32 + kg * 8 + (r & 3) * 2 + hi;
      if (k < 200) {
        int n = c >> 2, q = c & 3;
        int g = q * 200 + n;
        const float* W = dirv ? Wb : Wf;
        v = W[(256 + k) * 800 + g];
      }
    }
    WhA[id] = f2h(v);
    return;
  }
  id -= 401408;
  if (id < 1600) {                       // bcat[dir*800 + c] with same perm; +1 on f gate
    int dirv = id / 800;
    int c = id % 800;
    int n = c >> 2, q = c & 3;
    int g = q * 200 + n;
    bcat[id] = (dirv ? bbv : bfv)[g] + (q == 2 ? 1.f : 0.f);
  }
}

// ---------------- conv2 via rank-1 collapse (6 FMA/elem)
__global__ void conv2_kernel(const float* __restrict__ s, const float* __restrict__ PQ,
                             unsigned short* __restrict__ C2) {
  int row = blockIdx.x;
  int co  = threadIdx.x;
  int t = row & (T_LEN - 1);
  float s0 = s[row];
  float sm = (t > 0)         ? s[row - 1] : 0.f;
  float sp = (t < T_LEN - 1) ? s[row + 1] : 0.f;
  const float* P = PQ;
  const float* Q = PQ + 768;
  float acc = 0.f;
  float a, m;
  a = fmaxf(sm, 0.f); m = fmaxf(-sm, 0.f);
  acc += a * P[0*256+co] + m * Q[0*256+co];
  a = fmaxf(s0, 0.f); m = fmaxf(-s0, 0.f);
  acc += a * P[1*256+co] + m * Q[1*256+co];
  a = fmaxf(sp, 0.f); m = fmaxf(-sp, 0.f);
  acc += a * P[2*256+co] + m * Q[2*256+co];
  C2[(size_t)row * 256 + co] = f2h(fmaxf(acc, 0.f));
}

// ---------------- MFMA GEMM, K=256 fixed. B given TRANSPOSED [n][256].
// mode 0: direct rows; out = relu(acc) + relu(s*k1aw+k1ab)   (conv3+conv1a -> enc)
// mode 2: gathered rows (chain/time-chunk); out = acc + bcat[dir*800+col]
__global__ __launch_bounds__(256, 2) void gemm_kernel(
    const unsigned short* __restrict__ Ag, const unsigned short* __restrict__ Bg0,
    int N, int ntiles, int mode,
    unsigned short* __restrict__ Outp,
    const float* __restrict__ bias, const float* __restrict__ Sg,
    const float* __restrict__ k1aw, const float* __restrict__ k1ab,
    const int* __restrict__ lens, int t0)
{
  __shared__ __align__(16) unsigned short Bl[128*128]; // [n][k-phase], xor-swizzled 16B chunks
  __shared__ __align__(16) unsigned short Al[128*40];  // [m][k32], pad 40 halves
  __shared__ int rowsrc[128];
  int tid = threadIdx.x;
  int tm = blockIdx.x / ntiles, tn = blockIdx.x % ntiles;
  int col0 = tn * 128;
  int lane = tid & 63, wv = tid >> 6;
  int quad = lane >> 4, l16 = lane & 15;
  int wrow = (wv & 1) * 64, wcol = (wv >> 1) * 64;

  int dirv = 0;
  if (mode == 2) dirv = ((tm * 128) >> 8) >> 5;   // chain = m/TB ; dir = chain>>5
  const unsigned short* Bg = Bg0 + (size_t)dirv * 204800;

  if (tid < 128) {
    int r;
    if (mode == 2) {
      int m = tm * 128 + tid;
      int ch = m >> 8;              // TB=256
      int ls = m & 255;
      int b = ch & 31, dd = ch >> 5;
      int L = lens[b]; L = (L < 0) ? 0 : ((L > T_LEN) ? T_LEN : L);
      int t = t0 + ls;
      int src = dd ? (L - 1 - t) : t;
      src = (src < 0) ? 0 : ((src > T_LEN - 1) ? (T_LEN - 1) : src);
      r = b * T_LEN + src;
    } else {
      r = tm * 128 + tid;
    }
    rowsrc[tid] = r;
  }

  floatx4 acc[16];
  #pragma unroll
  for (int i = 0; i < 16; ++i) acc[i] = (floatx4){0.f,0.f,0.f,0.f};

  for (int ph = 0; ph < 2; ++ph) {
    __syncthreads();
    // stage B half-panel from BT: rows n in [col0,col0+128), k in [ph*128, +128)
    #pragma unroll
    for (int it = 0; it < 8; ++it) {
      int idx = it * 256 + tid;             // 2048 b128 chunks
      int n  = idx >> 4;                    // 0..127 local col
      int k8 = idx & 15;                    // 16B chunk within phase
      int nn = col0 + n;
      uint4 v = (uint4){0u,0u,0u,0u};
      if (nn < N) v = *(const uint4*)(Bg + (size_t)nn * 256 + ph * 128 + k8 * 8);
      *(uint4*)(&Bl[n * 128 + ((k8 ^ (n & 7)) * 8)]) = v;
    }
    for (int kb2 = 0; kb2 < 4; ++kb2) {
      int kb = ph * 4 + kb2;
      __syncthreads();
      #pragma unroll
      for (int i = 0; i < 2; ++i) {
        int c2 = i * 256 + tid;
        int r = c2 >> 2, kc = (c2 & 3) * 8;
        uint4 v = *(const uint4*)(Ag + (size_t)rowsrc[r] * 256 + kb * 32 + kc);
        *(uint4*)(&Al[r * 40 + kc]) = v;
      }
      __syncthreads();
      f16x8 af[4], bfr[4];
      #pragma unroll
      for (int mt = 0; mt < 4; ++mt)
        af[mt] = *(const f16x8*)(&Al[(wrow + mt*16 + l16) * 40 + quad * 8]);
      #pragma unroll
      for (int nt = 0; nt < 4; ++nt) {
        int nl = wcol + nt*16 + l16;
        int c = kb2 * 4 + quad;
        bfr[nt] = *(const f16x8*)(&Bl[nl * 128 + ((c ^ (nl & 7)) * 8)]);
      }
      #pragma unroll
      for (int mt = 0; mt < 4; ++mt)
        #pragma unroll
        for (int nt = 0; nt < 4; ++nt)
          acc[mt*4+nt] = __builtin_amdgcn_mfma_f32_16x16x32_f16(af[mt], bfr[nt], acc[mt*4+nt], 0, 0, 0);
    }
  }
  #pragma unroll
  for (int mt = 0; mt < 4; ++mt) {
    #pragma unroll
    for (int nt = 0; nt < 4; ++nt) {
      floatx4 v = acc[mt*4+nt];
      int col = col0 + wcol + nt*16 + l16;
      if (col < N) {
        #pragma unroll
        for (int r = 0; r < 4; ++r) {
          int row = tm * 128 + wrow + mt*16 + quad*4 + r;
          float x = v[r];
          float o;
          if (mode == 0) {
            float sv = Sg[row];
            float a1 = sv * k1aw[col] + k1ab[col];
            o = fmaxf(x, 0.f) + fmaxf(a1, 0.f);
          } else {
            o = x + bias[dirv * 800 + col];
          }
          Outp[(size_t)row * N + col] = f2h(o);
        }
      }
    }
  }
}

// ---------------- MFMA recurrent LSTM: one WG per (sample, direction), 512 thr (8 waves)
// Per step: z[800] = WhT[800x200] @ h[200] on the MATRIX pipe.
//   A = WhT tiles (rows = permuted gate-cols c=4n+q), B = h in col 0,
//   7x 16x16x32 f16 MFMA per tile (K padded 200->224). 56 col-tiles (50 real), 7/wave.
// KEY: B-fragment k-index doesn't depend on col (lane l needs h[kt*32+(l>>4)*8+j]).
//   Cols 1-15 of D are never read, so ALL 16 lanes of a k-group may receive the SAME
//   h values -> h is stored LINEARLY (224 halves) and fragment reads are 16-lane
//   BROADCAST ds_read_b128 (64B/instr instead of 1KB) — cuts the dominant LDS cost.
// D col-0 lanes (l&15==0) hold ALL FOUR gates of one unit in their 4 accum regs ->
//   z round-trips through a 3.6KB LDS buffer; 200 act lanes do 1x-redundant activation.
// Weights persist in registers: 7x28=196 VGPR/thread.
__global__ __launch_bounds__(512, 2)
void lstm_kernel(
    const unsigned short* __restrict__ XWbuf,  // [64][TB][800] f16, cols c=4n+q, bias(+1 f) folded
    const unsigned short* __restrict__ WhA,    // per-lane A-fragments (see prep)
    const int* __restrict__ lens,
    unsigned short* __restrict__ fwH, unsigned short* __restrict__ bwH,
    float* __restrict__ cState, unsigned short* __restrict__ hState,
    int t0)
{
  int ch  = blockIdx.x;
  int dir = ch >> 5;
  int b   = ch & 31;
  int L = lens[b];
  L = (L < 0) ? 0 : ((L > T_LEN) ? T_LEN : L);
  int tend = t0 + TB; if (tend > L) tend = L;
  int tid = threadIdx.x;
  int lane = tid & 63, w = tid >> 6;
  int p4 = lane >> 4;
  bool zlane = (lane & 15) == 0;

  __shared__ __align__(16) unsigned short xw_lds[2][SB*800]; // 25.6 KB
  __shared__ __align__(16) unsigned short hist[SB*200];      // 3.2 KB
  __shared__ __align__(16) unsigned short himg[224];         // linear h (+pad), 448 B
  __shared__ __align__(16) float zbuf[224*4];                // 3.6 KB z scratch

  // zero h (incl. k>=200 pad)
  if (tid < 112) ((unsigned int*)himg)[tid] = 0u;

  float c = 0.f;
  unsigned short last_h = 0;
  if (tid < 200 && t0 > 0) {
    c = cState[ch * HH + tid];
    last_h = hState[ch * HH + tid];
  }
  __syncthreads();
  if (tid < 200 && t0 > 0) himg[tid] = last_h;

  // load persistent A-fragments (7 col-tiles per wave; ct>=50 are zero dummies)
  f16x8 WA[7][7];
  #pragma unroll
  for (int i = 0; i < 7; ++i) {
    const uint4* wp = (const uint4*)WhA + ((size_t)((dir * 56 + (w * 7 + i)) * 64 + lane)) * 7;
    #pragma unroll
    for (int kt = 0; kt < 7; ++kt)
      WA[i][kt] = __builtin_bit_cast(f16x8, wp[kt]);
  }

  unsigned short* Hd = dir ? bwH : fwH;
  const unsigned short* XWc = XWbuf + ((size_t)ch * TB) * 800;

  // DMA block 0 into xw_lds[0]
  if (t0 < tend) {
    #pragma unroll
    for (int it = 0; it < 2; ++it) {
      int cidx = it * 512 + tid;
      if (cidx < 800)
        GLD_LDS16(XWc + (size_t)cidx * 8, &xw_lds[0][cidx * 8]);
    }
  }
  __syncthreads();   // h state visible to all B-frag readers

  int buf = 0;
  int prev_tb = -1, prev_cnt = 0;
  int ctb = w * 7;
  const unsigned short* hb_base = himg + p4 * 8;   // broadcast slice base for this lane

  for (int tb = t0; tb < tend; tb += SB) {
    int cnt = tend - tb; if (cnt > SB) cnt = SB;
    for (int sl = 0; sl < cnt; ++sl) {
      if (sl == 0) {
        // DMA next block into the other buffer (drains at a later barrier)
        int ntb = tb + SB;
        if ((ntb - t0) < TB) {
          const unsigned short* src = XWc + (size_t)(ntb - t0) * 800;
          #pragma unroll
          for (int it = 0; it < 2; ++it) {
            int cidx = it * 512 + tid;
            if (cidx < 800)
              GLD_LDS16(src + (size_t)cidx * 8, &xw_lds[buf ^ 1][cidx * 8]);
          }
        }
        // flush previous block's h history (reads drain at barrier 1 before rewrites)
        if (prev_tb >= 0) {
          int pcnt = prev_cnt;
          if (tid < pcnt * 25) {
            int srow = dir ? (pcnt - 1 - tid / 25) : (tid / 25);
            uint4 v = *(const uint4*)&hist[srow*200 + (tid % 25)*8];
            size_t base = dir ? ((size_t)(b*T_LEN + (L - prev_tb - pcnt)))*HH
                              : ((size_t)(b*T_LEN + prev_tb))*HH;
            *(uint4*)(Hd + base + (size_t)tid*8) = v;
          }
        }
      }
      // B fragments of h: 16-lane-group BROADCAST reads of the linear h array
      f16x8 hb[7];
      #pragma unroll
      for (int kt = 0; kt < 7; ++kt)
        hb[kt] = *(const f16x8*)(hb_base + kt * 32);

      // MFMA: 7 col-tiles, paired for ILP
      #pragma unroll
      for (int pr = 0; pr < 3; ++pr) {
        floatx4 C0 = (floatx4){0.f,0.f,0.f,0.f};
        floatx4 C1 = (floatx4){0.f,0.f,0.f,0.f};
        #pragma unroll
        for (int kt = 0; kt < 7; ++kt) {
          C0 = __builtin_amdgcn_mfma_f32_16x16x32_f16(WA[2*pr  ][kt], hb[kt], C0, 0, 0, 0);
          C1 = __builtin_amdgcn_mfma_f32_16x16x32_f16(WA[2*pr+1][kt], hb[kt], C1, 0, 0, 0);
        }
        if (zlane) {
          *(floatx4*)&zbuf[((ctb + 2*pr    ) * 4 + p4) * 4] = C0;
          *(floatx4*)&zbuf[((ctb + 2*pr + 1) * 4 + p4) * 4] = C1;
        }
      }
      {
        floatx4 C0 = (floatx4){0.f,0.f,0.f,0.f};
        #pragma unroll
        for (int kt = 0; kt < 7; ++kt)
          C0 = __builtin_amdgcn_mfma_f32_16x16x32_f16(WA[6][kt], hb[kt], C0, 0, 0, 0);
        if (zlane)
          *(floatx4*)&zbuf[((ctb + 6) * 4 + p4) * 4] = C0;
      }
      __syncthreads();   // z visible; h-frag regs already loaded -> h rewrite safe
      if (tid < 200) {
        floatx4 z = *(const floatx4*)&zbuf[tid * 4];
        uint2 xv = *(const uint2*)&xw_lds[buf][sl*800 + 4*tid];
        f16x2 xa = __builtin_bit_cast(f16x2, xv.x);
        f16x2 xb = __builtin_bit_cast(f16x2, xv.y);
        float zi = z[0] + (float)xa[0];
        float zj = z[1] + (float)xa[1];
        float zf = z[2] + (float)xb[0];
        float zo = z[3] + (float)xb[1];
        c = c * sigm(zf) + sigm(zi) * tanh_fast(zj);
        float h = tanh_fast(c) * sigm(zo);
        unsigned short hh = f2h(h);
        last_h = hh;
        himg[tid] = hh;
        hist[sl*200 + tid] = hh;
      }
      __syncthreads();   // new h visible for next step
    }
    prev_tb = tb; prev_cnt = cnt; buf ^= 1;
  }
  // final flush + state save
  if (prev_tb >= 0) {
    int pcnt = prev_cnt;
    if (tid < pcnt * 25) {
      int srow = dir ? (pcnt - 1 - tid / 25) : (tid / 25);
      uint4 v = *(const uint4*)&hist[srow*200 + (tid % 25)*8];
      size_t base = dir ? ((size_t)(b*T_LEN + (L - prev_tb - pcnt)))*HH
                        : ((size_t)(b*T_LEN + prev_tb))*HH;
      *(uint4*)(Hd + base + (size_t)tid*8) = v;
    }
  }
  if (tid < 200) {
    cState[ch * HH + tid] = c;
    hState[ch * HH + tid] = last_h;
  }
}

// ---------------- logits = [fwH|bwH] @ Wd + bd
__global__ __launch_bounds__(256) void out_kernel(
    const unsigned short* __restrict__ fwH, const unsigned short* __restrict__ bwH,
    const float* __restrict__ Wd, const float* __restrict__ bd, float* __restrict__ out)
{
  __shared__ float wd[2000];
  int tid = threadIdx.x;
  for (int i = tid; i < 2000; i += 256) wd[i] = Wd[i];
  __syncthreads();
  int row = blockIdx.x * 256 + tid;
  float acc0 = bd[0], acc1 = bd[1], acc2 = bd[2], acc3 = bd[3], acc4 = bd[4];
  const unsigned int* fu = (const unsigned int*)(fwH + (size_t)row * HH);
  const unsigned int* bu = (const unsigned int*)(bwH + (size_t)row * HH);
  #pragma unroll 4
  for (int i = 0; i < 100; ++i) {
    f16x2 pf = __builtin_bit_cast(f16x2, fu[i]);
    f16x2 pb = __builtin_bit_cast(f16x2, bu[i]);
    int k = 2 * i;
    float f0 = (float)pf[0], f1 = (float)pf[1];
    float b0 = (float)pb[0], b1 = (float)pb[1];
    const float* w0 = &wd[k*5];
    const float* w1 = &wd[(k+1)*5];
    const float* w2 = &wd[(200+k)*5];
    const float* w3 = &wd[(201+k)*5];
    acc0 += f0*w0[0] + f1*w1[0] + b0*w2[0] + b1*w3[0];
    acc1 += f0*w0[1] + f1*w1[1] + b0*w2[1] + b1*w3[1];
    acc2 += f0*w0[2] + f1*w1[2] + b0*w2[2] + b1*w3[2];
    acc3 += f0*w0[3] + f1*w1[3] + b0*w2[3] + b1*w3[3];
    acc4 += f0*w0[4] + f1*w1[4] + b0*w2[4] + b1*w3[4];
  }
  float* o = out + (size_t)row * 5;
  o[0]=acc0; o[1]=acc1; o[2]=acc2; o[3]=acc3; o[4]=acc4;
}

extern "C" void kernel_launch(void* const* d_in, const int* in_sizes, int n_in,
                              void* d_out, int out_size, void* d_ws, size_t ws_size,
                              hipStream_t stream)
{
  const float* signals = (const float*)d_in[0];
  const int*   lens    = (const int*)  d_in[1];
  const float* k1w     = (const float*)d_in[2];
  const float* k1aw    = (const float*)d_in[3];
  const float* k1ab    = (const float*)d_in[4];
  const float* k2w     = (const float*)d_in[5];
  const float* k3w     = (const float*)d_in[6];
  const float* Wf      = (const float*)d_in[7];
  const float* bf      = (const float*)d_in[8];
  const float* Wb      = (const float*)d_in[9];
  const float* bb      = (const float*)d_in[10];
  const float* Wd      = (const float*)d_in[11];
  const float* bd      = (const float*)d_in[12];
  float* out = (float*)d_out;
  char* ws = (char*)d_ws;

  // Region A aliases C2 (conv phase) and XWbuf (LSTM phase) — disjoint lifetimes.
  size_t szC2   = (size_t)NROWS * 256 * 2;          // 33,554,432
  size_t szXWb  = (size_t)64 * TB * 800 * 2;        // 26,214,400
  size_t szA    = (szC2 > szXWb) ? szC2 : szXWb;
  size_t oA   = 0;
  size_t oE   = oA   + szA;
  size_t oFw  = oE   + (size_t)NROWS*256*2;
  size_t oBw  = oFw  + (size_t)NROWS*HH*2;
  size_t oWhA = oBw  + (size_t)NROWS*HH*2;
  size_t oWx2 = oWhA + (size_t)2*56*64*28*4;        // 802,816
  size_t oK3  = oWx2 + (size_t)2*256*800*2;
  size_t oPQ  = oK3  + (size_t)256*256*2;
  size_t oBc  = oPQ  + 1536*4;
  size_t oCst = oBc  + 1600*4;
  size_t oHst = oCst + (size_t)64*HH*4;
  size_t total= oHst + (size_t)64*HH*2;
  if (ws_size < total) return;

  unsigned short* C2    = (unsigned short*)(ws + oA);
  unsigned short* XWbuf = (unsigned short*)(ws + oA);
  unsigned short* E     = (unsigned short*)(ws + oE);
  unsigned short* fwH   = (unsigned short*)(ws + oFw);
  unsigned short* bwH   = (unsigned short*)(ws + oBw);
  unsigned short* WhA   = (unsigned short*)(ws + oWhA);
  unsigned short* Wx2   = (unsigned short*)(ws + oWx2);
  unsigned short* K3h   = (unsigned short*)(ws + oK3);
  float* PQ     = (float*)(ws + oPQ);
  float* bcat   = (float*)(ws + oBc);
  float* cState = (float*)(ws + oCst);
  unsigned short* hState = (unsigned short*)(ws + oHst);

  (void)hipMemsetAsync(fwH, 0, (size_t)2*NROWS*HH*2, stream);
  pq_kernel  <<<6,     256, 0, stream>>>(k1w, k2w, PQ);
  prep_kernel<<<3431,  256, 0, stream>>>(k3w, Wf, bf, Wb, bb, K3h, Wx2, WhA, bcat);
  conv2_kernel<<<NROWS, 256, 0, stream>>>(signals, PQ, C2);
  gemm_kernel<<<1024,  256, 0, stream>>>(C2, K3h, 256, 2, 0, E, nullptr, signals, k1aw, k1ab, nullptr, 0);
  for (int t0 = 0; t0 < T_LEN; t0 += TB) {
    gemm_kernel<<<896, 256, 0, stream>>>(E, Wx2, 800, 7, 2, XWbuf, bcat, nullptr, nullptr, nullptr, lens, t0);
    lstm_kernel<<<64,  512, 0, stream>>>(XWbuf, WhA, lens, fwH, bwH, cState, hState, t0);
  }
  out_kernel <<<256,   256, 0, stream>>>(fwH, bwH, Wd, bd, out);
}

// Round 6
// 2726.672 us; speedup vs baseline: 1.1929x; 1.0521x over previous
//
#include <hip/hip_runtime.h>
#include <cstdint>

#define T_LEN 2048
#define NB    32
#define NROWS (NB*T_LEN)   // 65536
#define HH    200
#define G4    800
#define TB    256          // LSTM time-chunk (per dispatch)
#define SB    8            // step block staged in LDS

typedef _Float16 f16;
typedef _Float16 f16x2 __attribute__((ext_vector_type(2)));
typedef _Float16 f16x8 __attribute__((ext_vector_type(8)));
typedef float   floatx4 __attribute__((ext_vector_type(4)));

#define GLD_LDS16(g, l) __builtin_amdgcn_global_load_lds( \
    (const __attribute__((address_space(1))) void*)(g), \
    (__attribute__((address_space(3))) void*)(l), 16, 0, 0)

static __device__ __forceinline__ unsigned short f2h(float x) {
  f16 h = (f16)x; return __builtin_bit_cast(unsigned short, h);
}
static __device__ __forceinline__ float dot2f(unsigned int a, unsigned int b, float c) {
  return __builtin_amdgcn_fdot2(__builtin_bit_cast(f16x2, a),
                                __builtin_bit_cast(f16x2, b), c, false);
}
static __device__ __forceinline__ float sigm(float x) {
  return __builtin_amdgcn_rcpf(1.f + __expf(-x));
}
static __device__ __forceinline__ float tanh_fast(float x) {
  return 1.f - 2.f * __builtin_amdgcn_rcpf(__expf(2.f * x) + 1.f);
}

// ---------------- P/Q precompute: P[dt,co]=sum_ci relu(k1)k2, Q with relu(-k1)
__global__ void pq_kernel(const float* __restrict__ k1w, const float* __restrict__ k2w,
                          float* __restrict__ PQ) {
  int id = blockIdx.x * 256 + threadIdx.x;   // 1536 total
  int pq = id / 768;
  int rem = id % 768;
  int wdt = rem / 256;
  int co  = rem % 256;
  float acc = 0.f;
  for (int ci = 0; ci < 256; ++ci) {
    float k = k1w[ci];
    float kk = pq ? fmaxf(-k, 0.f) : fmaxf(k, 0.f);
    acc += kk * k2w[((size_t)wdt * 256 + ci) * 256 + co];
  }
  PQ[id] = acc;
}

// ---------------- f16 weight prep (B matrices stored TRANSPOSED: [n][k])
// K3T[co][ci] ; Wx2[dir][c][k] with permuted col c=4n+q (gate g=q*200+n) ;
// WhA: per-lane MFMA A-fragments of Wh^T, [dir][ct<56][lane<64][28 dwords]
//   (kernel uses k-tiles 0..5 only, k<192; dwords 24..27 unused) ;
// Wt: k-tail weights [dir][n<200][40 halves]: [q*8+j] = W[256+192+j][g], pad 32..39 ;
// bcat permuted, f-gate +1 folded.
__global__ void prep_kernel(const float* __restrict__ k3w,
                            const float* __restrict__ Wf, const float* __restrict__ bfv,
                            const float* __restrict__ Wb, const float* __restrict__ bbv,
                            unsigned short* __restrict__ K3h, unsigned short* __restrict__ Wx2,
                            unsigned short* __restrict__ WhA, float* __restrict__ bcat,
                            unsigned short* __restrict__ Wt) {
  int id = blockIdx.x * 256 + threadIdx.x;
  if (id < 65536) {                      // K3T[co*256+ci] = k3w[ci*256+co]
    K3h[id] = f2h(k3w[(id & 255) * 256 + (id >> 8)]);
    return;
  }
  id -= 65536;
  if (id < 409600) {                     // Wx2[dir][c<800][k<256]
    int dirv = id / 204800;
    int r = id % 204800;
    int c = r >> 8, k = r & 255;
    int n = c >> 2, q = c & 3;
    int g = q * 200 + n;
    const float* W = dirv ? Wb : Wf;
    Wx2[id] = f2h(W[k * 800 + g]);
    return;
  }
  id -= 409600;
  if (id < 401408) {                     // WhA halves: 2*56*64*28*2
    int hi = id & 1;
    int d  = id >> 1;                    // dword index
    int r  = d % 28;
    int t2 = d / 28;
    int lane = t2 & 63;
    int t3 = t2 >> 6;
    int ct = t3 % 56;
    int dirv = t3 / 56;
    int row = lane & 15;
    int kg  = lane >> 4;
    int c = ct * 16 + row;
    float v = 0.f;
    if (c < 800) {
      int kt = r >> 2;                   // 0..6
      int k = kt * 32 + kg * 8 + (r & 3) * 2 + hi;
      if (k < 200) {
        int n = c >> 2, q = c & 3;
        int g = q * 200 + n;
        const float* W = dirv ? Wb : Wf;
        v = W[(256 + k) * 800 + g];
      }
    }
    WhA[id] = f2h(v);
    return;
  }
  id -= 401408;
  if (id < 1600) {                       // bcat[dir*800 + c] with same perm; +1 on f gate
    int dirv = id / 800;
    int c = id % 800;
    int n = c >> 2, q = c & 3;
    int g = q * 200 + n;
    bcat[id] = (dirv ? bbv : bfv)[g] + (q == 2 ? 1.f : 0.f);
    return;
  }
  id -= 1600;
  if (id < 16000) {                      // Wt[dir][n][40]
    int dirv = id / 8000;
    int r = id % 8000;
    int n = r / 40, m = r % 40;
    float v = 0.f;
    if (m < 32) {
      int q = m >> 3, j = m & 7;
      int g = q * 200 + n;
      const float* W = dirv ? Wb : Wf;
      v = W[(256 + 192 + j) * 800 + g];
    }
    Wt[id] = f2h(v);
  }
}

// ---------------- conv2 via rank-1 collapse (6 FMA/elem)
__global__ void conv2_kernel(const float* __restrict__ s, const float* __restrict__ PQ,
                             unsigned short* __restrict__ C2) {
  int row = blockIdx.x;
  int co  = threadIdx.x;
  int t = row & (T_LEN - 1);
  float s0 = s[row];
  float sm = (t > 0)         ? s[row - 1] : 0.f;
  float sp = (t < T_LEN - 1) ? s[row + 1] : 0.f;
  const float* P = PQ;
  const float* Q = PQ + 768;
  float acc = 0.f;
  float a, m;
  a = fmaxf(sm, 0.f); m = fmaxf(-sm, 0.f);
  acc += a * P[0*256+co] + m * Q[0*256+co];
  a = fmaxf(s0, 0.f); m = fmaxf(-s0, 0.f);
  acc += a * P[1*256+co] + m * Q[1*256+co];
  a = fmaxf(sp, 0.f); m = fmaxf(-sp, 0.f);
  acc += a * P[2*256+co] + m * Q[2*256+co];
  C2[(size_t)row * 256 + co] = f2h(fmaxf(acc, 0.f));
}

// ---------------- MFMA GEMM, K=256 fixed. B given TRANSPOSED [n][256].
// mode 0: direct rows; out = relu(acc) + relu(s*k1aw+k1ab)   (conv3+conv1a -> enc)
// mode 2: gathered rows (chain/time-chunk); out = acc + bcat[dir*800+col]
__global__ __launch_bounds__(256, 2) void gemm_kernel(
    const unsigned short* __restrict__ Ag, const unsigned short* __restrict__ Bg0,
    int N, int ntiles, int mode,
    unsigned short* __restrict__ Outp,
    const float* __restrict__ bias, const float* __restrict__ Sg,
    const float* __restrict__ k1aw, const float* __restrict__ k1ab,
    const int* __restrict__ lens, int t0)
{
  __shared__ __align__(16) unsigned short Bl[128*128]; // [n][k-phase], xor-swizzled 16B chunks
  __shared__ __align__(16) unsigned short Al[128*40];  // [m][k32], pad 40 halves
  __shared__ int rowsrc[128];
  int tid = threadIdx.x;
  int tm = blockIdx.x / ntiles, tn = blockIdx.x % ntiles;
  int col0 = tn * 128;
  int lane = tid & 63, wv = tid >> 6;
  int quad = lane >> 4, l16 = lane & 15;
  int wrow = (wv & 1) * 64, wcol = (wv >> 1) * 64;

  int dirv = 0;
  if (mode == 2) dirv = ((tm * 128) >> 8) >> 5;   // chain = m/TB ; dir = chain>>5
  const unsigned short* Bg = Bg0 + (size_t)dirv * 204800;

  if (tid < 128) {
    int r;
    if (mode == 2) {
      int m = tm * 128 + tid;
      int ch = m >> 8;              // TB=256
      int ls = m & 255;
      int b = ch & 31, dd = ch >> 5;
      int L = lens[b]; L = (L < 0) ? 0 : ((L > T_LEN) ? T_LEN : L);
      int t = t0 + ls;
      int src = dd ? (L - 1 - t) : t;
      src = (src < 0) ? 0 : ((src > T_LEN - 1) ? (T_LEN - 1) : src);
      r = b * T_LEN + src;
    } else {
      r = tm * 128 + tid;
    }
    rowsrc[tid] = r;
  }

  floatx4 acc[16];
  #pragma unroll
  for (int i = 0; i < 16; ++i) acc[i] = (floatx4){0.f,0.f,0.f,0.f};

  for (int ph = 0; ph < 2; ++ph) {
    __syncthreads();
    // stage B half-panel from BT: rows n in [col0,col0+128), k in [ph*128, +128)
    #pragma unroll
    for (int it = 0; it < 8; ++it) {
      int idx = it * 256 + tid;             // 2048 b128 chunks
      int n  = idx >> 4;                    // 0..127 local col
      int k8 = idx & 15;                    // 16B chunk within phase
      int nn = col0 + n;
      uint4 v = (uint4){0u,0u,0u,0u};
      if (nn < N) v = *(const uint4*)(Bg + (size_t)nn * 256 + ph * 128 + k8 * 8);
      *(uint4*)(&Bl[n * 128 + ((k8 ^ (n & 7)) * 8)]) = v;
    }
    for (int kb2 = 0; kb2 < 4; ++kb2) {
      int kb = ph * 4 + kb2;
      __syncthreads();
      #pragma unroll
      for (int i = 0; i < 2; ++i) {
        int c2 = i * 256 + tid;
        int r = c2 >> 2, kc = (c2 & 3) * 8;
        uint4 v = *(const uint4*)(Ag + (size_t)rowsrc[r] * 256 + kb * 32 + kc);
        *(uint4*)(&Al[r * 40 + kc]) = v;
      }
      __syncthreads();
      f16x8 af[4], bfr[4];
      #pragma unroll
      for (int mt = 0; mt < 4; ++mt)
        af[mt] = *(const f16x8*)(&Al[(wrow + mt*16 + l16) * 40 + quad * 8]);
      #pragma unroll
      for (int nt = 0; nt < 4; ++nt) {
        int nl = wcol + nt*16 + l16;
        int c = kb2 * 4 + quad;
        bfr[nt] = *(const f16x8*)(&Bl[nl * 128 + ((c ^ (nl & 7)) * 8)]);
      }
      #pragma unroll
      for (int mt = 0; mt < 4; ++mt)
        #pragma unroll
        for (int nt = 0; nt < 4; ++nt)
          acc[mt*4+nt] = __builtin_amdgcn_mfma_f32_16x16x32_f16(af[mt], bfr[nt], acc[mt*4+nt], 0, 0, 0);
    }
  }
  #pragma unroll
  for (int mt = 0; mt < 4; ++mt) {
    #pragma unroll
    for (int nt = 0; nt < 4; ++nt) {
      floatx4 v = acc[mt*4+nt];
      int col = col0 + wcol + nt*16 + l16;
      if (col < N) {
        #pragma unroll
        for (int r = 0; r < 4; ++r) {
          int row = tm * 128 + wrow + mt*16 + quad*4 + r;
          float x = v[r];
          float o;
          if (mode == 0) {
            float sv = Sg[row];
            float a1 = sv * k1aw[col] + k1ab[col];
            o = fmaxf(x, 0.f) + fmaxf(a1, 0.f);
          } else {
            o = x + bias[dirv * 800 + col];
          }
          Outp[(size_t)row * N + col] = f2h(o);
        }
      }
    }
  }
}

// ---------------- MFMA recurrent LSTM: one WG per (sample, direction), 512 thr (8 waves)
// Per step: z[800] = WhT[800x200] @ h[200]; k<192 on the MATRIX pipe (6x 16x16x32 f16
// per col-tile, 7 col-tiles/wave), k=192..199 as a VALU dot2 tail on the 200 act
// threads (tail weights staged once in LDS). B = h broadcast (16-lane groups read the
// same linear h slice); D col-0 lanes hold all 4 gates of one unit.
// WEIGHT RESIDENCY IS THE POINT: WA = 7x6 f16x8 = 168 VGPR/thread, waves_per_eu(2,2)
// budgets 256, and an empty asm pin inside the step loop stops the compiler from
// sinking the loads into the loop (the R4/R5 failure mode: VGPR_Count=128 => weights
// re-streamed from L2 every step, ~2900 cyc/step invariant).
// h image double-buffered (read cur / write cur^1) so the tail read races nothing.
__global__ __launch_bounds__(512) __attribute__((amdgpu_waves_per_eu(2, 2)))
void lstm_kernel(
    const unsigned short* __restrict__ XWbuf,  // [64][TB][800] f16, cols c=4n+q, bias(+1 f) folded
    const unsigned short* __restrict__ WhA,    // per-lane A-fragments (see prep)
    const unsigned short* __restrict__ Wt,     // tail weights [dir][n][40]
    const int* __restrict__ lens,
    unsigned short* __restrict__ fwH, unsigned short* __restrict__ bwH,
    float* __restrict__ cState, unsigned short* __restrict__ hState,
    int t0)
{
  int ch  = blockIdx.x;
  int dir = ch >> 5;
  int b   = ch & 31;
  int L = lens[b];
  L = (L < 0) ? 0 : ((L > T_LEN) ? T_LEN : L);
  int tend = t0 + TB; if (tend > L) tend = L;
  int tid = threadIdx.x;
  int lane = tid & 63, w = tid >> 6;
  int p4 = lane >> 4;
  bool zlane = (lane & 15) == 0;

  __shared__ __align__(16) unsigned short xw_lds[2][SB*800]; // 25.6 KB
  __shared__ __align__(16) unsigned short hist[SB*200];      // 3.2 KB
  __shared__ __align__(16) unsigned short himg[2][224];      // linear h, double-buffered
  __shared__ __align__(16) float zbuf[224*4];                // 3.6 KB z scratch
  __shared__ __align__(16) unsigned short wtl[8000];         // 16 KB tail weights

  // zero both h buffers (incl. k>=200 pad)
  if (tid < 224) { ((unsigned int*)himg)[tid] = 0u; }

  float c = 0.f;
  unsigned short last_h = 0;
  if (tid < 200 && t0 > 0) {
    c = cState[ch * HH + tid];
    last_h = hState[ch * HH + tid];
  }
  __syncthreads();
  if (tid < 200 && t0 > 0) himg[0][tid] = last_h;

  // load persistent A-fragments (7 col-tiles per wave; k-tiles 0..5 only)
  f16x8 WA[7][6];
  #pragma unroll
  for (int i = 0; i < 7; ++i) {
    const uint4* wp = (const uint4*)WhA + ((size_t)((dir * 56 + (w * 7 + i)) * 64 + lane)) * 7;
    #pragma unroll
    for (int kt = 0; kt < 6; ++kt)
      WA[i][kt] = __builtin_bit_cast(f16x8, wp[kt]);
  }

  unsigned short* Hd = dir ? bwH : fwH;
  const unsigned short* XWc = XWbuf + ((size_t)ch * TB) * 800;
  const unsigned short* Wtg = Wt + dir * 8000;

  // stage tail weights (1000 chunks) + DMA xw block 0
  #pragma unroll
  for (int it = 0; it < 2; ++it) {
    int cidx = it * 512 + tid;
    if (cidx < 1000)
      GLD_LDS16(Wtg + (size_t)cidx * 8, &wtl[cidx * 8]);
  }
  if (t0 < tend) {
    #pragma unroll
    for (int it = 0; it < 2; ++it) {
      int cidx = it * 512 + tid;
      if (cidx < 800)
        GLD_LDS16(XWc + (size_t)cidx * 8, &xw_lds[0][cidx * 8]);
    }
  }
  __syncthreads();   // drains staging DMA; h state visible

  int buf = 0, cur = 0;
  int prev_tb = -1, prev_cnt = 0;
  int ctb = w * 7;

  for (int tb = t0; tb < tend; tb += SB) {
    int cnt = tend - tb; if (cnt > SB) cnt = SB;
    for (int sl = 0; sl < cnt; ++sl) {
      if (sl == 0) {
        // DMA next block into the other buffer (drains at a later barrier)
        int ntb = tb + SB;
        if ((ntb - t0) < TB) {
          const unsigned short* src = XWc + (size_t)(ntb - t0) * 800;
          #pragma unroll
          for (int it = 0; it < 2; ++it) {
            int cidx = it * 512 + tid;
            if (cidx < 800)
              GLD_LDS16(src + (size_t)cidx * 8, &xw_lds[buf ^ 1][cidx * 8]);
          }
        }
        // flush previous block's h history
        if (prev_tb >= 0) {
          int pcnt = prev_cnt;
          if (tid < pcnt * 25) {
            int srow = dir ? (pcnt - 1 - tid / 25) : (tid / 25);
            uint4 v = *(const uint4*)&hist[srow*200 + (tid % 25)*8];
            size_t base = dir ? ((size_t)(b*T_LEN + (L - prev_tb - pcnt)))*HH
                              : ((size_t)(b*T_LEN + prev_tb))*HH;
            *(uint4*)(Hd + base + (size_t)tid*8) = v;
          }
        }
      }
      // keep the persistent weight fragments live (defeat load-sinking)
      #pragma unroll
      for (int i = 0; i < 7; ++i)
        #pragma unroll
        for (int kt = 0; kt < 6; ++kt)
          asm volatile("" : "+v"(WA[i][kt]));

      // B fragments of h: 16-lane-group BROADCAST reads of the linear h array
      const unsigned short* hb_base = &himg[cur][p4 * 8];
      f16x8 hb[6];
      #pragma unroll
      for (int kt = 0; kt < 6; ++kt)
        hb[kt] = *(const f16x8*)(hb_base + kt * 32);

      // MFMA: 7 col-tiles, paired for ILP
      #pragma unroll
      for (int pr = 0; pr < 3; ++pr) {
        floatx4 C0 = (floatx4){0.f,0.f,0.f,0.f};
        floatx4 C1 = (floatx4){0.f,0.f,0.f,0.f};
        #pragma unroll
        for (int kt = 0; kt < 6; ++kt) {
          C0 = __builtin_amdgcn_mfma_f32_16x16x32_f16(WA[2*pr  ][kt], hb[kt], C0, 0, 0, 0);
          C1 = __builtin_amdgcn_mfma_f32_16x16x32_f16(WA[2*pr+1][kt], hb[kt], C1, 0, 0, 0);
        }
        if (zlane) {
          *(floatx4*)&zbuf[((ctb + 2*pr    ) * 4 + p4) * 4] = C0;
          *(floatx4*)&zbuf[((ctb + 2*pr + 1) * 4 + p4) * 4] = C1;
        }
      }
      {
        floatx4 C0 = (floatx4){0.f,0.f,0.f,0.f};
        #pragma unroll
        for (int kt = 0; kt < 6; ++kt)
          C0 = __builtin_amdgcn_mfma_f32_16x16x32_f16(WA[6][kt], hb[kt], C0, 0, 0, 0);
        if (zlane)
          *(floatx4*)&zbuf[((ctb + 6) * 4 + p4) * 4] = C0;
      }
      __syncthreads();   // z visible
      if (tid < 200) {
        floatx4 z = *(const floatx4*)&zbuf[tid * 4];
        uint2 xv = *(const uint2*)&xw_lds[buf][sl*800 + 4*tid];
        // k=192..199 tail: h tail broadcast + per-unit tail weights from LDS
        uint4 ht = *(const uint4*)&himg[cur][192];
        const uint4* wtp = (const uint4*)(wtl + tid * 40);
        uint4 wq0 = wtp[0], wq1 = wtp[1], wq2 = wtp[2], wq3 = wtp[3];
        f16x2 xa = __builtin_bit_cast(f16x2, xv.x);
        f16x2 xb = __builtin_bit_cast(f16x2, xv.y);
        float zi = z[0] + (float)xa[0];
        float zj = z[1] + (float)xa[1];
        float zf = z[2] + (float)xb[0];
        float zo = z[3] + (float)xb[1];
        zi = dot2f(ht.x, wq0.x, dot2f(ht.y, wq0.y, dot2f(ht.z, wq0.z, dot2f(ht.w, wq0.w, zi))));
        zj = dot2f(ht.x, wq1.x, dot2f(ht.y, wq1.y, dot2f(ht.z, wq1.z, dot2f(ht.w, wq1.w, zj))));
        zf = dot2f(ht.x, wq2.x, dot2f(ht.y, wq2.y, dot2f(ht.z, wq2.z, dot2f(ht.w, wq2.w, zf))));
        zo = dot2f(ht.x, wq3.x, dot2f(ht.y, wq3.y, dot2f(ht.z, wq3.z, dot2f(ht.w, wq3.w, zo))));
        c = c * sigm(zf) + sigm(zi) * tanh_fast(zj);
        float h = tanh_fast(c) * sigm(zo);
        unsigned short hh = f2h(h);
        last_h = hh;
        himg[cur ^ 1][tid] = hh;
        hist[sl*200 + tid] = hh;
      }
      cur ^= 1;
      __syncthreads();   // new h visible for next step
    }
    prev_tb = tb; prev_cnt = cnt; buf ^= 1;
  }
  // final flush + state save
  if (prev_tb >= 0) {
    int pcnt = prev_cnt;
    if (tid < pcnt * 25) {
      int srow = dir ? (pcnt - 1 - tid / 25) : (tid / 25);
      uint4 v = *(const uint4*)&hist[srow*200 + (tid % 25)*8];
      size_t base = dir ? ((size_t)(b*T_LEN + (L - prev_tb - pcnt)))*HH
                        : ((size_t)(b*T_LEN + prev_tb))*HH;
      *(uint4*)(Hd + base + (size_t)tid*8) = v;
    }
  }
  if (tid < 200) {
    cState[ch * HH + tid] = c;
    hState[ch * HH + tid] = last_h;
  }
}

// ---------------- logits = [fwH|bwH] @ Wd + bd
__global__ __launch_bounds__(256) void out_kernel(
    const unsigned short* __restrict__ fwH, const unsigned short* __restrict__ bwH,
    const float* __restrict__ Wd, const float* __restrict__ bd, float* __restrict__ out)
{
  __shared__ float wd[2000];
  int tid = threadIdx.x;
  for (int i = tid; i < 2000; i += 256) wd[i] = Wd[i];
  __syncthreads();
  int row = blockIdx.x * 256 + tid;
  float acc0 = bd[0], acc1 = bd[1], acc2 = bd[2], acc3 = bd[3], acc4 = bd[4];
  const unsigned int* fu = (const unsigned int*)(fwH + (size_t)row * HH);
  const unsigned int* bu = (const unsigned int*)(bwH + (size_t)row * HH);
  #pragma unroll 4
  for (int i = 0; i < 100; ++i) {
    f16x2 pf = __builtin_bit_cast(f16x2, fu[i]);
    f16x2 pb = __builtin_bit_cast(f16x2, bu[i]);
    int k = 2 * i;
    float f0 = (float)pf[0], f1 = (float)pf[1];
    float b0 = (float)pb[0], b1 = (float)pb[1];
    const float* w0 = &wd[k*5];
    const float* w1 = &wd[(k+1)*5];
    const float* w2 = &wd[(200+k)*5];
    const float* w3 = &wd[(201+k)*5];
    acc0 += f0*w0[0] + f1*w1[0] + b0*w2[0] + b1*w3[0];
    acc1 += f0*w0[1] + f1*w1[1] + b0*w2[1] + b1*w3[1];
    acc2 += f0*w0[2] + f1*w1[2] + b0*w2[2] + b1*w3[2];
    acc3 += f0*w0[3] + f1*w1[3] + b0*w2[3] + b1*w3[3];
    acc4 += f0*w0[4] + f1*w1[4] + b0*w2[4] + b1*w3[4];
  }
  float* o = out + (size_t)row * 5;
  o[0]=acc0; o[1]=acc1; o[2]=acc2; o[3]=acc3; o[4]=acc4;
}

extern "C" void kernel_launch(void* const* d_in, const int* in_sizes, int n_in,
                              void* d_out, int out_size, void* d_ws, size_t ws_size,
                              hipStream_t stream)
{
  const float* signals = (const float*)d_in[0];
  const int*   lens    = (const int*)  d_in[1];
  const float* k1w     = (const float*)d_in[2];
  const float* k1aw    = (const float*)d_in[3];
  const float* k1ab    = (const float*)d_in[4];
  const float* k2w     = (const float*)d_in[5];
  const float* k3w     = (const float*)d_in[6];
  const float* Wf      = (const float*)d_in[7];
  const float* bf      = (const float*)d_in[8];
  const float* Wb      = (const float*)d_in[9];
  const float* bb      = (const float*)d_in[10];
  const float* Wd      = (const float*)d_in[11];
  const float* bd      = (const float*)d_in[12];
  float* out = (float*)d_out;
  char* ws = (char*)d_ws;

  // Region A aliases C2 (conv phase) and XWbuf (LSTM phase) — disjoint lifetimes.
  size_t szC2   = (size_t)NROWS * 256 * 2;          // 33,554,432
  size_t szXWb  = (size_t)64 * TB * 800 * 2;        // 26,214,400
  size_t szA    = (szC2 > szXWb) ? szC2 : szXWb;
  size_t oA   = 0;
  size_t oE   = oA   + szA;
  size_t oFw  = oE   + (size_t)NROWS*256*2;
  size_t oBw  = oFw  + (size_t)NROWS*HH*2;
  size_t oWhA = oBw  + (size_t)NROWS*HH*2;
  size_t oWx2 = oWhA + (size_t)2*56*64*28*4;        // 802,816
  size_t oK3  = oWx2 + (size_t)2*256*800*2;
  size_t oPQ  = oK3  + (size_t)256*256*2;
  size_t oBc  = oPQ  + 1536*4;
  size_t oCst = oBc  + 1600*4;
  size_t oHst = oCst + (size_t)64*HH*4;
  size_t oWt  = oHst + (size_t)64*HH*2;
  size_t total= oWt  + (size_t)16000*2;
  if (ws_size < total) return;

  unsigned short* C2    = (unsigned short*)(ws + oA);
  unsigned short* XWbuf = (unsigned short*)(ws + oA);
  unsigned short* E     = (unsigned short*)(ws + oE);
  unsigned short* fwH   = (unsigned short*)(ws + oFw);
  unsigned short* bwH   = (unsigned short*)(ws + oBw);
  unsigned short* WhA   = (unsigned short*)(ws + oWhA);
  unsigned short* Wx2   = (unsigned short*)(ws + oWx2);
  unsigned short* K3h   = (unsigned short*)(ws + oK3);
  float* PQ     = (float*)(ws + oPQ);
  float* bcat   = (float*)(ws + oBc);
  float* cState = (float*)(ws + oCst);
  unsigned short* hState = (unsigned short*)(ws + oHst);
  unsigned short* Wt     = (unsigned short*)(ws + oWt);

  (void)hipMemsetAsync(fwH, 0, (size_t)2*NROWS*HH*2, stream);
  pq_kernel  <<<6,     256, 0, stream>>>(k1w, k2w, PQ);
  prep_kernel<<<3493,  256, 0, stream>>>(k3w, Wf, bf, Wb, bb, K3h, Wx2, WhA, bcat, Wt);
  conv2_kernel<<<NROWS, 256, 0, stream>>>(signals, PQ, C2);
  gemm_kernel<<<1024,  256, 0, stream>>>(C2, K3h, 256, 2, 0, E, nullptr, signals, k1aw, k1ab, nullptr, 0);
  for (int t0 = 0; t0 < T_LEN; t0 += TB) {
    gemm_kernel<<<896, 256, 0, stream>>>(E, Wx2, 800, 7, 2, XWbuf, bcat, nullptr, nullptr, nullptr, lens, t0);
    lstm_kernel<<<64,  512, 0, stream>>>(XWbuf, WhA, Wt, lens, fwH, bwH, cState, hState, t0);
  }
  out_kernel <<<256,   256, 0, stream>>>(fwH, bwH, Wd, bd, out);
}